// Round 1
// baseline (2819.003 us; speedup 1.0000x reference)
//
#include <hip/hip_runtime.h>
#include <math.h>

#define C_IN  256
#define HH    100
#define WW    100
#define HW    10000
#define NBAT  4
#define COUTC 256
#define K9    9
#define GG    32
#define TPN   157           // pixel-tiles (of 64) per batch image: ceil(10000/64)
#define EPSF  1e-5f

// ---------------------------------------------------------------------------
// k0: transpose w_def (COUT, C, 9) -> Wt (C, 9, COUT)  [o contiguous]
// ---------------------------------------------------------------------------
__global__ void __launch_bounds__(256) k0_transpose(const float* __restrict__ wd,
                                                    float* __restrict__ wt) {
  int i = blockIdx.x * 256 + threadIdx.x;          // < 256*9*256 = 589824
  int c = i / (K9 * COUTC);
  int r = i % (K9 * COUTC);
  int k = r / COUTC;
  int o = r % COUTC;
  wt[i] = wd[((size_t)o * C_IN + c) * K9 + k];
}

// ---------------------------------------------------------------------------
// k1: offset conv (6 channels) -> sampling positions posy/posx (N,9,H,W)
// block = 256 thr = 4 waves; 64 pixels per block, each wave does 64 channels
// ---------------------------------------------------------------------------
__global__ void __launch_bounds__(256) k1_offsets(
    const float* __restrict__ x, const float* __restrict__ w_tm,
    const float* __restrict__ b_tm, const float* __restrict__ w_tr,
    const float* __restrict__ b_tr, float* __restrict__ posy,
    float* __restrict__ posx) {
  const int tid  = threadIdx.x;
  const int lane = tid & 63;
  const int q    = tid >> 6;
  const int flat = blockIdx.x * 64 + lane;         // 0..39999, grid=625 exact
  const int n    = flat / HW;
  const int pix  = flat % HW;
  const int h = pix / WW, w = pix % WW;

  float acc[6] = {0.f, 0.f, 0.f, 0.f, 0.f, 0.f};
  const float* xn = x + (size_t)n * C_IN * HW;
  const int c0 = q * 64;

  for (int cc = 0; cc < 64; ++cc) {
    const int c = c0 + cc;
    const float* xp = xn + (size_t)c * HW;
    float xv[9];
#pragma unroll
    for (int ky = 0; ky < 3; ++ky) {
      const int y  = h + ky - 1;
      const bool yv = ((unsigned)y < (unsigned)HH);
      const int yc = min(max(y, 0), HH - 1);
#pragma unroll
      for (int kx = 0; kx < 3; ++kx) {
        const int xw = w + kx - 1;
        const bool v = yv && ((unsigned)xw < (unsigned)WW);
        const int xc = min(max(xw, 0), WW - 1);
        float val = xp[yc * WW + xc];              // clamped addr: always safe
        xv[ky * 3 + kx] = v ? val : 0.f;           // zero-pad via select
      }
    }
#pragma unroll
    for (int ch = 0; ch < 4; ++ch) {
      const float* wp = w_tm + ((size_t)ch * C_IN + c) * K9;  // uniform -> s_load
#pragma unroll
      for (int t = 0; t < 9; ++t) acc[ch] = fmaf(xv[t], wp[t], acc[ch]);
    }
#pragma unroll
    for (int ch = 0; ch < 2; ++ch) {
      const float* wp = w_tr + ((size_t)ch * C_IN + c) * K9;
#pragma unroll
      for (int t = 0; t < 9; ++t) acc[4 + ch] = fmaf(xv[t], wp[t], acc[4 + ch]);
    }
  }

  __shared__ float red[4][6][64];
#pragma unroll
  for (int ch = 0; ch < 6; ++ch) red[q][ch][lane] = acc[ch];
  __syncthreads();

  if (q == 0) {
    float s[6];
#pragma unroll
    for (int ch = 0; ch < 6; ++ch) {
      float v = 0.f;
#pragma unroll
      for (int qq = 0; qq < 4; ++qq) v += red[qq][ch][lane];
      s[ch] = v;
    }
    const float A00 = s[0] + b_tm[0], A01 = s[1] + b_tm[1];
    const float A10 = s[2] + b_tm[2], A11 = s[3] + b_tm[3];
    const float t0 = s[4] + b_tr[0], t1 = s[5] + b_tr[1];
    // ys_k = h + tr0 + A00*ry + A01*rx ; xs_k = w + tr1 + A10*ry + A11*rx
    const float fh = (float)h, fw = (float)w;
#pragma unroll
    for (int k = 0; k < 9; ++k) {
      const float ry = (float)(k / 3 - 1);
      const float rx = (float)(k % 3 - 1);
      posy[((size_t)n * K9 + k) * HW + pix] = fh + t0 + A00 * ry + A01 * rx;
      posx[((size_t)n * K9 + k) * HW + pix] = fw + t1 + A10 * ry + A11 * rx;
    }
  }
}

// ---------------------------------------------------------------------------
// k2: deformable conv. block = 256 thr = 4 waves x 16 pixels (64 px/block).
// Each lane: To=4 outputs (o = 4*lane..4*lane+3) x Tp=16 pixels.
// Chunked K: 16 channels x 9 taps staged in LDS per chunk.
// Also emits per-block GroupNorm partial sums (deterministic).
// ---------------------------------------------------------------------------
#define ACC4(p, sval)                                  \
  acc[p][0] = fmaf(wvv.x, (sval), acc[p][0]);          \
  acc[p][1] = fmaf(wvv.y, (sval), acc[p][1]);          \
  acc[p][2] = fmaf(wvv.z, (sval), acc[p][2]);          \
  acc[p][3] = fmaf(wvv.w, (sval), acc[p][3]);

__global__ void __launch_bounds__(256) k2_deform(
    const float* __restrict__ x, const float* __restrict__ wt,
    const float* __restrict__ posy, const float* __restrict__ posx,
    float* __restrict__ out, float* __restrict__ part) {
  const int b = blockIdx.x;                 // grid = 4*157 = 628
  const int n = b / TPN, t = b % TPN;
  const int pbase = t * 64;
  const int tid = threadIdx.x;
  const int lane = tid & 63, wv_id = tid >> 6;

  __shared__ __align__(16) float S[16 * 576];   // [c][k*64+j]  36.9 KB
  __shared__ int   sa[4][576];                  // corner addrs (clamped, safe)
  __shared__ float swt[4][576];                 // corner weights (0 if invalid)
  __shared__ float gred[2][4][32];

  // --- precompute bilinear corners per (k, j) ---
  for (int s = tid; s < 576; s += 256) {
    const int k = s >> 6, j = s & 63;
    const int pix = pbase + j;
    int a[4] = {0, 0, 0, 0};
    float wg[4] = {0.f, 0.f, 0.f, 0.f};
    if (pix < HW) {
      const float ys = posy[((size_t)n * K9 + k) * HW + pix];
      const float xs = posx[((size_t)n * K9 + k) * HW + pix];
      const float y0f = floorf(ys), x0f = floorf(xs);
      const float wy = ys - y0f, wx = xs - x0f;
      const int iy0 = (int)y0f, ix0 = (int)x0f;
#pragma unroll
      for (int aa = 0; aa < 2; ++aa) {
#pragma unroll
        for (int bb = 0; bb < 2; ++bb) {
          const int iy = iy0 + aa, ix = ix0 + bb;
          const bool v = ((unsigned)iy < (unsigned)HH) && ((unsigned)ix < (unsigned)WW);
          a[aa * 2 + bb] = v ? (iy * WW + ix) : 0;
          wg[aa * 2 + bb] = v ? (aa ? wy : 1.f - wy) * (bb ? wx : 1.f - wx) : 0.f;
        }
      }
    }
#pragma unroll
    for (int cr = 0; cr < 4; ++cr) { sa[cr][s] = a[cr]; swt[cr][s] = wg[cr]; }
  }
  __syncthreads();

  // fixed (k,j) pairs per thread: s = tid, tid+256, (tid+512 for tid<64)
  const int s0 = tid, s1 = tid + 256, s2 = tid + 512;
  const bool has2 = (tid < 64);
  const int a00 = sa[0][s0], a01 = sa[1][s0], a02 = sa[2][s0], a03 = sa[3][s0];
  const int a10 = sa[0][s1], a11 = sa[1][s1], a12 = sa[2][s1], a13 = sa[3][s1];
  const float w00 = swt[0][s0], w01 = swt[1][s0], w02 = swt[2][s0], w03 = swt[3][s0];
  const float w10 = swt[0][s1], w11 = swt[1][s1], w12 = swt[2][s1], w13 = swt[3][s1];
  int a20 = 0, a21 = 0, a22 = 0, a23 = 0;
  float w20 = 0.f, w21 = 0.f, w22 = 0.f, w23 = 0.f;
  if (has2) {
    a20 = sa[0][s2]; a21 = sa[1][s2]; a22 = sa[2][s2]; a23 = sa[3][s2];
    w20 = swt[0][s2]; w21 = swt[1][s2]; w22 = swt[2][s2]; w23 = swt[3][s2];
  }

  float acc[16][4];
#pragma unroll
  for (int p = 0; p < 16; ++p) {
#pragma unroll
    for (int oo = 0; oo < 4; ++oo) acc[p][oo] = 0.f;
  }

  const float* xn = x + (size_t)n * C_IN * HW;

  for (int c0 = 0; c0 < C_IN; c0 += 16) {
    // --- gather chunk into LDS ---
    const float* xb = xn + (size_t)c0 * HW;
#pragma unroll 4
    for (int c = 0; c < 16; ++c) {
      const float* xc = xb + (size_t)c * HW;
      S[c * 576 + s0] = w00 * xc[a00] + w01 * xc[a01] + w02 * xc[a02] + w03 * xc[a03];
      S[c * 576 + s1] = w10 * xc[a10] + w11 * xc[a11] + w12 * xc[a12] + w13 * xc[a13];
      if (has2)
        S[c * 576 + s2] = w20 * xc[a20] + w21 * xc[a21] + w22 * xc[a22] + w23 * xc[a23];
    }
    __syncthreads();

    // --- register-tiled compute ---
#pragma unroll 2
    for (int c = 0; c < 16; ++c) {
      const float* Sc = &S[c * 576 + wv_id * 16];
#pragma unroll
      for (int k = 0; k < 9; ++k) {
        const float4 wvv =
            *(const float4*)(wt + ((size_t)((c0 + c) * K9 + k)) * COUTC + (lane << 2));
        const float* Sp = Sc + k * 64;
#pragma unroll
        for (int p4 = 0; p4 < 4; ++p4) {
          const float4 sv = *(const float4*)(Sp + (p4 << 2));
          ACC4(p4 * 4 + 0, sv.x)
          ACC4(p4 * 4 + 1, sv.y)
          ACC4(p4 * 4 + 2, sv.z)
          ACC4(p4 * 4 + 3, sv.w)
        }
      }
    }
    __syncthreads();
  }

  // --- write raw conv output + GN partial sums ---
  float ps1 = 0.f, ps2 = 0.f;
#pragma unroll
  for (int p = 0; p < 16; ++p) {
    const int pix = pbase + wv_id * 16 + p;
    if (pix < HW) {
#pragma unroll
      for (int oo = 0; oo < 4; ++oo) {
        const float v = acc[p][oo];
        out[((size_t)(n * COUTC + (lane << 2) + oo)) * HW + pix] = v;
        ps1 += v;
        ps2 += v * v;
      }
    }
  }
  // lanes (2g, 2g+1) hold group g (8 channels); reduce pair then waves
  ps1 += __shfl_xor(ps1, 1);
  ps2 += __shfl_xor(ps2, 1);
  if ((lane & 1) == 0) {
    gred[0][wv_id][lane >> 1] = ps1;
    gred[1][wv_id][lane >> 1] = ps2;
  }
  __syncthreads();
  if (tid < 32) {
    float a1 = 0.f, a2 = 0.f;
#pragma unroll
    for (int q = 0; q < 4; ++q) { a1 += gred[0][q][tid]; a2 += gred[1][q][tid]; }
    float* pp = part + (((size_t)n * TPN + t) * GG + tid) * 2;
    pp[0] = a1;
    pp[1] = a2;
  }
}

// ---------------------------------------------------------------------------
// k3: reduce partials -> per (n,g) mean & rsigma
// ---------------------------------------------------------------------------
__global__ void __launch_bounds__(64) k3_stats(const float* __restrict__ part,
                                               float* __restrict__ stats) {
  const int b = blockIdx.x;                // 0..127
  const int n = b >> 5, g = b & 31;
  double s = 0.0, q = 0.0;
  for (int i = threadIdx.x; i < TPN; i += 64) {
    const float* pp = part + (((size_t)n * TPN + i) * GG + g) * 2;
    s += pp[0];
    q += pp[1];
  }
#pragma unroll
  for (int off = 32; off > 0; off >>= 1) {
    s += __shfl_down(s, off);
    q += __shfl_down(q, off);
  }
  if (threadIdx.x == 0) {
    const double cnt = 8.0 * (double)HW;   // 80000 elems per group
    const double mean = s / cnt;
    const double var = q / cnt - mean * mean;
    stats[b * 2 + 0] = (float)mean;
    stats[b * 2 + 1] = (float)(1.0 / sqrt(var + (double)EPSF));
  }
}

// ---------------------------------------------------------------------------
// k4: in-place GroupNorm affine + ReLU on d_out
// ---------------------------------------------------------------------------
__global__ void __launch_bounds__(256) k4_norm(float* __restrict__ out,
                                               const float* __restrict__ stats,
                                               const float* __restrict__ gw,
                                               const float* __restrict__ gb) {
  const size_t i4 = (size_t)blockIdx.x * 256 + threadIdx.x;  // grid=10000 exact
  const size_t idx = i4 * 4;
  const int n = (int)(idx / ((size_t)COUTC * HW));
  const int r = (int)(idx % ((size_t)COUTC * HW));
  const int o = r / HW;
  const int g = o >> 3;
  const float mean = stats[(n * GG + g) * 2 + 0];
  const float rs = stats[(n * GG + g) * 2 + 1];
  const float sc = rs * gw[o];
  const float sh = gb[o] - mean * sc;
  float4 v = *(float4*)(out + idx);
  v.x = fmaxf(fmaf(v.x, sc, sh), 0.f);
  v.y = fmaxf(fmaf(v.y, sc, sh), 0.f);
  v.z = fmaxf(fmaf(v.z, sc, sh), 0.f);
  v.w = fmaxf(fmaf(v.w, sc, sh), 0.f);
  *(float4*)(out + idx) = v;
}

// ---------------------------------------------------------------------------
extern "C" void kernel_launch(void* const* d_in, const int* in_sizes, int n_in,
                              void* d_out, int out_size, void* d_ws, size_t ws_size,
                              hipStream_t stream) {
  const float* x    = (const float*)d_in[0];
  const float* w_tm = (const float*)d_in[1];
  const float* b_tm = (const float*)d_in[2];
  const float* w_tr = (const float*)d_in[3];
  const float* b_tr = (const float*)d_in[4];
  const float* w_def = (const float*)d_in[5];
  const float* gn_w = (const float*)d_in[6];
  const float* gn_b = (const float*)d_in[7];
  float* out = (float*)d_out;
  float* ws = (float*)d_ws;

  float* posy  = ws;                       // 360000
  float* posx  = ws + 360000;              // 360000
  float* wt    = ws + 720000;              // 589824
  float* part  = ws + 1309824;             // 4*157*32*2 = 40192
  float* stats = ws + 1350016;             // 256
  // total: 1350272 floats = 5.15 MB of ws

  hipLaunchKernelGGL(k0_transpose, dim3(2304), dim3(256), 0, stream, w_def, wt);
  hipLaunchKernelGGL(k1_offsets, dim3(625), dim3(256), 0, stream,
                     x, w_tm, b_tm, w_tr, b_tr, posy, posx);
  hipLaunchKernelGGL(k2_deform, dim3(NBAT * TPN), dim3(256), 0, stream,
                     x, wt, posy, posx, out, part);
  hipLaunchKernelGGL(k3_stats, dim3(NBAT * GG), dim3(64), 0, stream, part, stats);
  hipLaunchKernelGGL(k4_norm, dim3(10000), dim3(256), 0, stream,
                     out, stats, gn_w, gn_b);
}

// Round 2
// 552.589 us; speedup vs baseline: 5.1014x; 5.1014x over previous
//
#include <hip/hip_runtime.h>
#include <math.h>

#define C_IN  256
#define HH    100
#define WW    100
#define HW    10000
#define NBAT  4
#define COUTC 256
#define K9    9
#define GG    32
#define PTS   313          // ceil(10000/32) pixel-tiles (of 32) per image
#define EPSF  1e-5f

typedef __bf16 bf16x8 __attribute__((ext_vector_type(8)));
typedef float  f32x4  __attribute__((ext_vector_type(4)));

__device__ __forceinline__ unsigned short f2bf(float f) {
  unsigned int u = __builtin_bit_cast(unsigned int, f);
  u += 0x7FFFu + ((u >> 16) & 1u);
  return (unsigned short)(u >> 16);
}

// ---------------------------------------------------------------------------
// k0: build A-fragment-ordered bf16 weights.
// chunk q = tap*8 + cg (72 chunks of K=32 channels at fixed tap).
// Wfrag[q][ot 0..15][lane 0..63][j 0..7]:
//   o = ot*16 + (lane&15), c = cg*32 + (lane>>4)*8 + j
// ---------------------------------------------------------------------------
__global__ void __launch_bounds__(256) k0_wfrag(const float* __restrict__ wd,
                                                unsigned short* __restrict__ wf) {
  const int i = blockIdx.x * 256 + threadIdx.x;   // < 72*16*64*8 = 589824
  const int j  = i & 7;
  const int l  = (i >> 3) & 63;
  const int ot = (i >> 9) & 15;
  const int q  = i >> 13;
  const int tap = q >> 3, cg = q & 7;
  const int o = ot * 16 + (l & 15);
  const int c = cg * 32 + (l >> 4) * 8 + j;
  wf[i] = f2bf(wd[((size_t)o * C_IN + c) * K9 + tap]);
}

// ---------------------------------------------------------------------------
// k1: offset conv (6 channels) -> sampling positions posy/posx (N,9,H,W)
// ---------------------------------------------------------------------------
__global__ void __launch_bounds__(256) k1_offsets(
    const float* __restrict__ x, const float* __restrict__ w_tm,
    const float* __restrict__ b_tm, const float* __restrict__ w_tr,
    const float* __restrict__ b_tr, float* __restrict__ posy,
    float* __restrict__ posx) {
  const int tid  = threadIdx.x;
  const int lane = tid & 63;
  const int q    = tid >> 6;
  const int flat = blockIdx.x * 64 + lane;         // grid=625 exact
  const int n    = flat / HW;
  const int pix  = flat % HW;
  const int h = pix / WW, w = pix % WW;

  float acc[6] = {0.f, 0.f, 0.f, 0.f, 0.f, 0.f};
  const float* xn = x + (size_t)n * C_IN * HW;
  const int c0 = q * 64;

  for (int cc = 0; cc < 64; ++cc) {
    const int c = c0 + cc;
    const float* xp = xn + (size_t)c * HW;
    float xv[9];
#pragma unroll
    for (int ky = 0; ky < 3; ++ky) {
      const int y  = h + ky - 1;
      const bool yv = ((unsigned)y < (unsigned)HH);
      const int yc = min(max(y, 0), HH - 1);
#pragma unroll
      for (int kx = 0; kx < 3; ++kx) {
        const int xw = w + kx - 1;
        const bool v = yv && ((unsigned)xw < (unsigned)WW);
        const int xc = min(max(xw, 0), WW - 1);
        float val = xp[yc * WW + xc];
        xv[ky * 3 + kx] = v ? val : 0.f;
      }
    }
#pragma unroll
    for (int ch = 0; ch < 4; ++ch) {
      const float* wp = w_tm + ((size_t)ch * C_IN + c) * K9;
#pragma unroll
      for (int t = 0; t < 9; ++t) acc[ch] = fmaf(xv[t], wp[t], acc[ch]);
    }
#pragma unroll
    for (int ch = 0; ch < 2; ++ch) {
      const float* wp = w_tr + ((size_t)ch * C_IN + c) * K9;
#pragma unroll
      for (int t = 0; t < 9; ++t) acc[4 + ch] = fmaf(xv[t], wp[t], acc[4 + ch]);
    }
  }

  __shared__ float red[4][6][64];
#pragma unroll
  for (int ch = 0; ch < 6; ++ch) red[q][ch][lane] = acc[ch];
  __syncthreads();

  if (q == 0) {
    float s[6];
#pragma unroll
    for (int ch = 0; ch < 6; ++ch) {
      float v = 0.f;
#pragma unroll
      for (int qq = 0; qq < 4; ++qq) v += red[qq][ch][lane];
      s[ch] = v;
    }
    const float A00 = s[0] + b_tm[0], A01 = s[1] + b_tm[1];
    const float A10 = s[2] + b_tm[2], A11 = s[3] + b_tm[3];
    const float t0 = s[4] + b_tr[0], t1 = s[5] + b_tr[1];
    const float fh = (float)h, fw = (float)w;
#pragma unroll
    for (int k = 0; k < 9; ++k) {
      const float ry = (float)(k / 3 - 1);
      const float rx = (float)(k % 3 - 1);
      posy[((size_t)n * K9 + k) * HW + pix] = fh + t0 + A00 * ry + A01 * rx;
      posx[((size_t)n * K9 + k) * HW + pix] = fw + t1 + A10 * ry + A11 * rx;
    }
  }
}

// ---------------------------------------------------------------------------
// k2: deformable conv as bf16 MFMA GEMM.
// Block: 32 px x 256 couts, 256 thr = 4 waves (wave owns 64 couts x 32 px).
// K = 2304 as 72 chunks (tap-major): chunk q = tap*8+cg -> 32 channels.
// Per chunk: gather-stage B (32px x 32k bf16) into LDS, A-frags direct from
// pre-swizzled global wfrag; 8 mfma_f32_16x16x32_bf16 per wave.
// Epilogue: coalesced stores + GroupNorm partial sums.
// ---------------------------------------------------------------------------
__global__ void __launch_bounds__(256) k2_deform(
    const float* __restrict__ x, const unsigned short* __restrict__ wfrag,
    const float* __restrict__ posy, const float* __restrict__ posx,
    float* __restrict__ out, float* __restrict__ part) {
  const int b = blockIdx.x;                 // grid = 4*313 = 1252
  const int n = b / PTS, t = b % PTS;
  const int pbase = t * 32;
  const int tid = threadIdx.x;
  const int lane = tid & 63, wv = tid >> 6;

  __shared__ __align__(16) unsigned short Bs[32 * 40];  // [px][40] pad->2-way free
  __shared__ int   soff[9][32][4];
  __shared__ float swt_[9][32][4];
  __shared__ float gr1[4][4][64];
  __shared__ float gr2[4][4][64];

  // --- phase 0: bilinear corners per (tap, px) ---
  for (int s = tid; s < 288; s += 256) {
    const int tap = s >> 5, px = s & 31;
    const int pix = pbase + px;
    int a[4] = {0, 0, 0, 0};
    float wg[4] = {0.f, 0.f, 0.f, 0.f};
    if (pix < HW) {
      const float ys = posy[((size_t)n * K9 + tap) * HW + pix];
      const float xs = posx[((size_t)n * K9 + tap) * HW + pix];
      const float y0f = floorf(ys), x0f = floorf(xs);
      const float wy = ys - y0f, wx = xs - x0f;
      const int iy0 = (int)y0f, ix0 = (int)x0f;
#pragma unroll
      for (int aa = 0; aa < 2; ++aa) {
#pragma unroll
        for (int bb = 0; bb < 2; ++bb) {
          const int iy = iy0 + aa, ix = ix0 + bb;
          const bool v = ((unsigned)iy < (unsigned)HH) && ((unsigned)ix < (unsigned)WW);
          a[aa * 2 + bb] = v ? (iy * WW + ix) : 0;
          wg[aa * 2 + bb] = v ? (aa ? wy : 1.f - wy) * (bb ? wx : 1.f - wx) : 0.f;
        }
      }
    }
#pragma unroll
    for (int cr = 0; cr < 4; ++cr) { soff[tap][px][cr] = a[cr]; swt_[tap][px][cr] = wg[cr]; }
  }
  __syncthreads();

  f32x4 acc[4][2];
#pragma unroll
  for (int tt = 0; tt < 4; ++tt)
#pragma unroll
    for (int bt = 0; bt < 2; ++bt) acc[tt][bt] = (f32x4)(0.f);

  const float* xn = x + (size_t)n * C_IN * HW;
  const int px = tid & 31;          // staging pixel
  const int q4 = tid >> 5;          // staging channel-quad 0..7
  const char* bread = (const char*)Bs + (lane & 15) * 80 + (lane >> 4) * 16;
  char* bwrite = (char*)Bs + px * 80 + q4 * 8;

  int qq = 0;
  for (int tap = 0; tap < 9; ++tap) {
    const int o0 = soff[tap][px][0], o1 = soff[tap][px][1];
    const int o2 = soff[tap][px][2], o3 = soff[tap][px][3];
    const float cw0 = swt_[tap][px][0], cw1 = swt_[tap][px][1];
    const float cw2 = swt_[tap][px][2], cw3 = swt_[tap][px][3];
    for (int cg = 0; cg < 8; ++cg, ++qq) {
      // --- stage B: 4 channels per thread, bilinear gather ---
      const float* xp = xn + (size_t)(cg * 32 + q4 * 4) * HW;
      float v0 = cw0 * xp[o0] + cw1 * xp[o1] + cw2 * xp[o2] + cw3 * xp[o3];
      xp += HW;
      float v1 = cw0 * xp[o0] + cw1 * xp[o1] + cw2 * xp[o2] + cw3 * xp[o3];
      xp += HW;
      float v2 = cw0 * xp[o0] + cw1 * xp[o1] + cw2 * xp[o2] + cw3 * xp[o3];
      xp += HW;
      float v3 = cw0 * xp[o0] + cw1 * xp[o1] + cw2 * xp[o2] + cw3 * xp[o3];
      uint2 pk;
      pk.x = (unsigned)f2bf(v0) | ((unsigned)f2bf(v1) << 16);
      pk.y = (unsigned)f2bf(v2) | ((unsigned)f2bf(v3) << 16);
      *(uint2*)bwrite = pk;
      __syncthreads();

      // --- MFMA: A from global frag layout, B from LDS ---
      const unsigned short* wfp = wfrag + ((size_t)(qq * 16 + wv * 4) * 64 + lane) * 8;
      bf16x8 a0 = *(const bf16x8*)(wfp);
      bf16x8 a1 = *(const bf16x8*)(wfp + 512);
      bf16x8 a2 = *(const bf16x8*)(wfp + 1024);
      bf16x8 a3 = *(const bf16x8*)(wfp + 1536);
      bf16x8 b0 = *(const bf16x8*)(bread);
      bf16x8 b1 = *(const bf16x8*)(bread + 1280);
      acc[0][0] = __builtin_amdgcn_mfma_f32_16x16x32_bf16(a0, b0, acc[0][0], 0, 0, 0);
      acc[0][1] = __builtin_amdgcn_mfma_f32_16x16x32_bf16(a0, b1, acc[0][1], 0, 0, 0);
      acc[1][0] = __builtin_amdgcn_mfma_f32_16x16x32_bf16(a1, b0, acc[1][0], 0, 0, 0);
      acc[1][1] = __builtin_amdgcn_mfma_f32_16x16x32_bf16(a1, b1, acc[1][1], 0, 0, 0);
      acc[2][0] = __builtin_amdgcn_mfma_f32_16x16x32_bf16(a2, b0, acc[2][0], 0, 0, 0);
      acc[2][1] = __builtin_amdgcn_mfma_f32_16x16x32_bf16(a2, b1, acc[2][1], 0, 0, 0);
      acc[3][0] = __builtin_amdgcn_mfma_f32_16x16x32_bf16(a3, b0, acc[3][0], 0, 0, 0);
      acc[3][1] = __builtin_amdgcn_mfma_f32_16x16x32_bf16(a3, b1, acc[3][1], 0, 0, 0);
      __syncthreads();
    }
  }

  // --- epilogue: coalesced stores + GN partials ---
  // D layout: col(px16) = lane&15, row(o) = (lane>>4)*4 + reg
  const int prow = (lane >> 4) * 4;
#pragma unroll
  for (int tt = 0; tt < 4; ++tt) {
    float s1 = 0.f, s2 = 0.f;
#pragma unroll
    for (int bt = 0; bt < 2; ++bt) {
      const int pix = pbase + bt * 16 + (lane & 15);
      const int ob = wv * 64 + tt * 16 + prow;
      if (pix < HW) {
        float* op = out + ((size_t)(n * COUTC + ob)) * HW + pix;
#pragma unroll
        for (int r = 0; r < 4; ++r) op[(size_t)r * HW] = acc[tt][bt][r];
      }
#pragma unroll
      for (int r = 0; r < 4; ++r) {
        const float v = acc[tt][bt][r];
        s1 += v;
        s2 += v * v;
      }
    }
    gr1[wv][tt][lane] = s1;
    gr2[wv][tt][lane] = s2;
  }
  __syncthreads();
  if (tid < 32) {
    const int wv2 = tid >> 3, tt2 = (tid >> 1) & 3, h = tid & 1;
    float a1 = 0.f, a2 = 0.f;
#pragma unroll 8
    for (int i = 0; i < 32; ++i) {
      a1 += gr1[wv2][tt2][h * 32 + i];
      a2 += gr2[wv2][tt2][h * 32 + i];
    }
    float* pp = part + (((size_t)n * PTS + t) * GG + tid) * 2;
    pp[0] = a1;
    pp[1] = a2;
  }
}

// ---------------------------------------------------------------------------
// k3: reduce partials -> per (n,g) mean & rsigma
// ---------------------------------------------------------------------------
__global__ void __launch_bounds__(64) k3_stats(const float* __restrict__ part,
                                               float* __restrict__ stats) {
  const int b = blockIdx.x;                // 0..127
  const int n = b >> 5, g = b & 31;
  double s = 0.0, q = 0.0;
  for (int i = threadIdx.x; i < PTS; i += 64) {
    const float* pp = part + (((size_t)n * PTS + i) * GG + g) * 2;
    s += pp[0];
    q += pp[1];
  }
#pragma unroll
  for (int off = 32; off > 0; off >>= 1) {
    s += __shfl_down(s, off);
    q += __shfl_down(q, off);
  }
  if (threadIdx.x == 0) {
    const double cnt = 8.0 * (double)HW;   // 80000 elems per group
    const double mean = s / cnt;
    const double var = q / cnt - mean * mean;
    stats[b * 2 + 0] = (float)mean;
    stats[b * 2 + 1] = (float)(1.0 / sqrt(var + (double)EPSF));
  }
}

// ---------------------------------------------------------------------------
// k4: in-place GroupNorm affine + ReLU on d_out
// ---------------------------------------------------------------------------
__global__ void __launch_bounds__(256) k4_norm(float* __restrict__ out,
                                               const float* __restrict__ stats,
                                               const float* __restrict__ gw,
                                               const float* __restrict__ gb) {
  const size_t i4 = (size_t)blockIdx.x * 256 + threadIdx.x;  // grid=10000 exact
  const size_t idx = i4 * 4;
  const int n = (int)(idx / ((size_t)COUTC * HW));
  const int r = (int)(idx % ((size_t)COUTC * HW));
  const int o = r / HW;
  const int g = o >> 3;
  const float mean = stats[(n * GG + g) * 2 + 0];
  const float rs = stats[(n * GG + g) * 2 + 1];
  const float sc = rs * gw[o];
  const float sh = gb[o] - mean * sc;
  float4 v = *(float4*)(out + idx);
  v.x = fmaxf(fmaf(v.x, sc, sh), 0.f);
  v.y = fmaxf(fmaf(v.y, sc, sh), 0.f);
  v.z = fmaxf(fmaf(v.z, sc, sh), 0.f);
  v.w = fmaxf(fmaf(v.w, sc, sh), 0.f);
  *(float4*)(out + idx) = v;
}

// ---------------------------------------------------------------------------
extern "C" void kernel_launch(void* const* d_in, const int* in_sizes, int n_in,
                              void* d_out, int out_size, void* d_ws, size_t ws_size,
                              hipStream_t stream) {
  const float* x    = (const float*)d_in[0];
  const float* w_tm = (const float*)d_in[1];
  const float* b_tm = (const float*)d_in[2];
  const float* w_tr = (const float*)d_in[3];
  const float* b_tr = (const float*)d_in[4];
  const float* w_def = (const float*)d_in[5];
  const float* gn_w = (const float*)d_in[6];
  const float* gn_b = (const float*)d_in[7];
  float* out = (float*)d_out;
  float* ws = (float*)d_ws;

  float* posy  = ws;                                  // 360000 floats
  float* posx  = ws + 360000;                         // 360000 floats
  unsigned short* wfrag = (unsigned short*)(ws + 720000);  // 589824 bf16 = 294912 fl
  float* part  = ws + 720000 + 294912;                // 4*313*32*2 = 80128 floats
  float* stats = ws + 1095040;                        // 256 floats
  // total ~4.4 MB of ws

  hipLaunchKernelGGL(k0_wfrag, dim3(2304), dim3(256), 0, stream, w_def, wfrag);
  hipLaunchKernelGGL(k1_offsets, dim3(625), dim3(256), 0, stream,
                     x, w_tm, b_tm, w_tr, b_tr, posy, posx);
  hipLaunchKernelGGL(k2_deform, dim3(NBAT * PTS), dim3(256), 0, stream,
                     x, wfrag, posy, posx, out, part);
  hipLaunchKernelGGL(k3_stats, dim3(NBAT * GG), dim3(64), 0, stream, part, stats);
  hipLaunchKernelGGL(k4_norm, dim3(10000), dim3(256), 0, stream,
                     out, stats, gn_w, gn_b);
}

// Round 3
// 250.183 us; speedup vs baseline: 11.2678x; 2.2087x over previous
//
#include <hip/hip_runtime.h>
#include <math.h>

#define C_IN  256
#define HH    100
#define WW    100
#define HW    10000
#define NBAT  4
#define COUTC 256
#define K9    9
#define GG    32
#define TILES 13           // 13x13 tiles of 8x8 pixels per image
#define NT2   169
#define EPSF  1e-5f

typedef _Float16 f16x8 __attribute__((ext_vector_type(8)));
typedef _Float16 h2v   __attribute__((ext_vector_type(2)));
typedef float    f32x4 __attribute__((ext_vector_type(4)));

// ---------------------------------------------------------------------------
// k0: build A-fragment-ordered fp16 weights.
// chunk q = tap*8 + cg (72 chunks of K=32 channels at fixed tap).
// Wfrag[q][ot 0..15][lane 0..63][j 0..7]:
//   o = ot*16 + (lane&15), c = cg*32 + (lane>>4)*8 + j
// ---------------------------------------------------------------------------
__global__ void __launch_bounds__(256) k0_wfrag(const float* __restrict__ wd,
                                                _Float16* __restrict__ wf) {
  const int i = blockIdx.x * 256 + threadIdx.x;   // < 72*16*64*8 = 589824
  const int j  = i & 7;
  const int l  = (i >> 3) & 63;
  const int ot = (i >> 9) & 15;
  const int q  = i >> 13;
  const int tap = q >> 3, cg = q & 7;
  const int o = ot * 16 + (l & 15);
  const int c = cg * 32 + (l >> 4) * 8 + j;
  wf[i] = (_Float16)wd[((size_t)o * C_IN + c) * K9 + tap];
}

// ---------------------------------------------------------------------------
// kt: transpose x (N,C,H,W) f32 -> xh (N,H,W,C) fp16
// block: 64 ch x 64 px tile via LDS
// ---------------------------------------------------------------------------
__global__ void __launch_bounds__(256) kt_nhwc(const float* __restrict__ x,
                                               _Float16* __restrict__ xh) {
  __shared__ float T[64][65];
  const int b = blockIdx.x;                 // 4n * 4cg * 157 = 2512
  const int n = b / (4 * 157);
  const int r = b % (4 * 157);
  const int cg = r / 157, tile = r % 157;
  const int pbase = tile * 64, c0 = cg * 64;
  const int tid = threadIdx.x, lane = tid & 63, wv = tid >> 6;

#pragma unroll 4
  for (int i = 0; i < 16; ++i) {
    const int c = c0 + wv * 16 + i;
    const int pix = pbase + lane;
    T[wv * 16 + i][lane] = (pix < HW) ? x[((size_t)n * C_IN + c) * HW + pix] : 0.f;
  }
  __syncthreads();

  const int cl = tid & 15;
#pragma unroll
  for (int j = 0; j < 4; ++j) {
    const int pxl = (tid >> 4) + j * 16;
    const int pix = pbase + pxl;
    if (pix < HW) {
      const float v0 = T[cl * 4 + 0][pxl], v1 = T[cl * 4 + 1][pxl];
      const float v2 = T[cl * 4 + 2][pxl], v3 = T[cl * 4 + 3][pxl];
      uint2 pk;
      h2v a = {(_Float16)v0, (_Float16)v1};
      h2v bq = {(_Float16)v2, (_Float16)v3};
      pk.x = __builtin_bit_cast(unsigned, a);
      pk.y = __builtin_bit_cast(unsigned, bq);
      *(uint2*)(xh + ((size_t)n * HW + pix) * C_IN + c0 + cl * 4) = pk;
    }
  }
}

// ---------------------------------------------------------------------------
// k1: offset conv (6 channels) -> sampling positions posy/posx (N,9,H,W)
// ---------------------------------------------------------------------------
__global__ void __launch_bounds__(256) k1_offsets(
    const float* __restrict__ x, const float* __restrict__ w_tm,
    const float* __restrict__ b_tm, const float* __restrict__ w_tr,
    const float* __restrict__ b_tr, float* __restrict__ posy,
    float* __restrict__ posx) {
  const int tid  = threadIdx.x;
  const int lane = tid & 63;
  const int q    = tid >> 6;
  const int flat = blockIdx.x * 64 + lane;         // grid=625 exact
  const int n    = flat / HW;
  const int pix  = flat % HW;
  const int h = pix / WW, w = pix % WW;

  float acc[6] = {0.f, 0.f, 0.f, 0.f, 0.f, 0.f};
  const float* xn = x + (size_t)n * C_IN * HW;
  const int c0 = q * 64;

  for (int cc = 0; cc < 64; ++cc) {
    const int c = c0 + cc;
    const float* xp = xn + (size_t)c * HW;
    float xv[9];
#pragma unroll
    for (int ky = 0; ky < 3; ++ky) {
      const int y  = h + ky - 1;
      const bool yv = ((unsigned)y < (unsigned)HH);
      const int yc = min(max(y, 0), HH - 1);
#pragma unroll
      for (int kx = 0; kx < 3; ++kx) {
        const int xw = w + kx - 1;
        const bool v = yv && ((unsigned)xw < (unsigned)WW);
        const int xc = min(max(xw, 0), WW - 1);
        float val = xp[yc * WW + xc];
        xv[ky * 3 + kx] = v ? val : 0.f;
      }
    }
#pragma unroll
    for (int ch = 0; ch < 4; ++ch) {
      const float* wp = w_tm + ((size_t)ch * C_IN + c) * K9;
#pragma unroll
      for (int t = 0; t < 9; ++t) acc[ch] = fmaf(xv[t], wp[t], acc[ch]);
    }
#pragma unroll
    for (int ch = 0; ch < 2; ++ch) {
      const float* wp = w_tr + ((size_t)ch * C_IN + c) * K9;
#pragma unroll
      for (int t = 0; t < 9; ++t) acc[4 + ch] = fmaf(xv[t], wp[t], acc[4 + ch]);
    }
  }

  __shared__ float red[4][6][64];
#pragma unroll
  for (int ch = 0; ch < 6; ++ch) red[q][ch][lane] = acc[ch];
  __syncthreads();

  if (q == 0) {
    float s[6];
#pragma unroll
    for (int ch = 0; ch < 6; ++ch) {
      float v = 0.f;
#pragma unroll
      for (int qq = 0; qq < 4; ++qq) v += red[qq][ch][lane];
      s[ch] = v;
    }
    const float A00 = s[0] + b_tm[0], A01 = s[1] + b_tm[1];
    const float A10 = s[2] + b_tm[2], A11 = s[3] + b_tm[3];
    const float t0 = s[4] + b_tr[0], t1 = s[5] + b_tr[1];
    const float fh = (float)h, fw = (float)w;
#pragma unroll
    for (int k = 0; k < 9; ++k) {
      const float ry = (float)(k / 3 - 1);
      const float rx = (float)(k % 3 - 1);
      posy[((size_t)n * K9 + k) * HW + pix] = fh + t0 + A00 * ry + A01 * rx;
      posx[((size_t)n * K9 + k) * HW + pix] = fw + t1 + A10 * ry + A11 * rx;
    }
  }
}

// ---------------------------------------------------------------------------
// k2: deformable conv as fp16 MFMA GEMM over NHWC-gathered B.
// Block: 8x8 px tile (64 px) x 256 couts, 4 waves (wave: 64 couts x 64 px).
// K = 2304 as 72 chunks (tap-major). Per chunk: NHWC fp16 gather (4 corner
// dwordx4 loads/thread, pk_fma combine) -> LDS double buffer, 16 MFMA/wave.
// Issue-early/combine-late: corner loads for chunk i+1 issue before MFMAs
// of chunk i. One barrier per chunk.
// ---------------------------------------------------------------------------
__global__ void __launch_bounds__(256) k2_deform(
    const _Float16* __restrict__ xh, const _Float16* __restrict__ wfrag,
    const float* __restrict__ posy, const float* __restrict__ posx,
    float* __restrict__ out, float* __restrict__ part) {
  const int b = blockIdx.x;                 // grid = 4*169 = 676
  const int n = b / NT2, rem = b % NT2;
  const int ty = rem / TILES, tx = rem % TILES;
  const int tid = threadIdx.x;
  const int lane = tid & 63, wv = tid >> 6;

  __shared__ __align__(16) unsigned int Bs[2][64 * 20];  // [px][20u]=40 fp16, 80B row
  __shared__ float gr1[4][4][64];
  __shared__ float gr2[4][4][64];

  // staging role: px = tid>>2 (0..63), qq = tid&3 (8 channels each)
  const int spx = tid >> 2, qq = tid & 3;
  const int srow = ty * 8 + (spx >> 3), scol = tx * 8 + (spx & 7);
  const bool pv = (srow < HH) && (scol < WW);
  const int mypix = srow * WW + scol;

  const _Float16* xnh = xh + (size_t)n * HW * C_IN;

  int ca0, ca1, ca2, ca3;
  h2v cw0, cw1, cw2, cw3;

#define CORNERS(tap)                                                          \
  {                                                                           \
    float ys = 0.f, xs = 0.f;                                                 \
    if (pv) {                                                                 \
      ys = posy[((size_t)n * K9 + (tap)) * HW + mypix];                       \
      xs = posx[((size_t)n * K9 + (tap)) * HW + mypix];                       \
    }                                                                         \
    const float y0f = floorf(ys), x0f = floorf(xs);                           \
    const float wy = ys - y0f, wx = xs - x0f;                                 \
    const int iy0 = (int)y0f, ix0 = (int)x0f;                                 \
    const bool vy0 = ((unsigned)iy0 < (unsigned)HH);                          \
    const bool vy1 = ((unsigned)(iy0 + 1) < (unsigned)HH);                    \
    const bool vx0 = ((unsigned)ix0 < (unsigned)WW);                          \
    const bool vx1 = ((unsigned)(ix0 + 1) < (unsigned)WW);                    \
    const bool v0 = pv && vy0 && vx0, v1 = pv && vy0 && vx1;                  \
    const bool v2 = pv && vy1 && vx0, v3 = pv && vy1 && vx1;                  \
    ca0 = (v0 ? (iy0 * WW + ix0) : 0) * C_IN + qq * 8;                        \
    ca1 = (v1 ? (iy0 * WW + ix0 + 1) : 0) * C_IN + qq * 8;                    \
    ca2 = (v2 ? ((iy0 + 1) * WW + ix0) : 0) * C_IN + qq * 8;                  \
    ca3 = (v3 ? ((iy0 + 1) * WW + ix0 + 1) : 0) * C_IN + qq * 8;              \
    float g0 = v0 ? (1.f - wy) * (1.f - wx) : 0.f;                            \
    float g1 = v1 ? (1.f - wy) * wx : 0.f;                                    \
    float g2 = v2 ? wy * (1.f - wx) : 0.f;                                    \
    float g3 = v3 ? wy * wx : 0.f;                                            \
    _Float16 h0 = (_Float16)g0, h1 = (_Float16)g1;                            \
    _Float16 h2_ = (_Float16)g2, h3 = (_Float16)g3;                           \
    cw0 = (h2v){h0, h0}; cw1 = (h2v){h1, h1};                                 \
    cw2 = (h2v){h2_, h2_}; cw3 = (h2v){h3, h3};                               \
  }

#define LOADC(cg, r0, r1, r2, r3)                                             \
  {                                                                           \
    const _Float16* bp = xnh + ((cg) << 5);                                   \
    r0 = *(const uint4*)(bp + ca0);                                           \
    r1 = *(const uint4*)(bp + ca1);                                           \
    r2 = *(const uint4*)(bp + ca2);                                           \
    r3 = *(const uint4*)(bp + ca3);                                           \
  }

#define CMB1(c, r0, r1, r2, r3)                                               \
  __builtin_bit_cast(unsigned,                                                \
      (h2v)(cw0 * __builtin_bit_cast(h2v, r0.c) +                             \
            cw1 * __builtin_bit_cast(h2v, r1.c) +                             \
            cw2 * __builtin_bit_cast(h2v, r2.c) +                             \
            cw3 * __builtin_bit_cast(h2v, r3.c)))

  f32x4 acc[4][4];
#pragma unroll
  for (int tt = 0; tt < 4; ++tt)
#pragma unroll
    for (int bt = 0; bt < 4; ++bt) acc[tt][bt] = (f32x4)(0.f);

  // prologue: chunk 0
  {
    CORNERS(0)
    uint4 r0, r1, r2, r3;
    LOADC(0, r0, r1, r2, r3)
    uint4 v;
    v.x = CMB1(x, r0, r1, r2, r3);
    v.y = CMB1(y, r0, r1, r2, r3);
    v.z = CMB1(z, r0, r1, r2, r3);
    v.w = CMB1(w, r0, r1, r2, r3);
    *(uint4*)(&Bs[0][spx * 20 + qq * 4]) = v;
  }
  __syncthreads();

#pragma unroll 2
  for (int i = 0; i < 72; ++i) {
    uint4 r0, r1, r2, r3;
    const int j = i + 1;
    const bool hn = (j < 72);
    if (hn) {
      if ((j & 7) == 0) CORNERS(j >> 3)
      LOADC(j & 7, r0, r1, r2, r3)
    }

    // MFMA on chunk i
    {
      const _Float16* wfp = wfrag + (((size_t)(i * 16 + wv * 4) * 64 + lane) << 3);
      f16x8 a0 = *(const f16x8*)(wfp);
      f16x8 a1 = *(const f16x8*)(wfp + 512);
      f16x8 a2 = *(const f16x8*)(wfp + 1024);
      f16x8 a3 = *(const f16x8*)(wfp + 1536);
      const _Float16* bb =
          (const _Float16*)&Bs[i & 1][0] + (lane & 15) * 40 + (lane >> 4) * 8;
#pragma unroll
      for (int bt = 0; bt < 4; ++bt) {
        f16x8 bf = *(const f16x8*)(bb + bt * 640);
        acc[0][bt] = __builtin_amdgcn_mfma_f32_16x16x32_f16(a0, bf, acc[0][bt], 0, 0, 0);
        acc[1][bt] = __builtin_amdgcn_mfma_f32_16x16x32_f16(a1, bf, acc[1][bt], 0, 0, 0);
        acc[2][bt] = __builtin_amdgcn_mfma_f32_16x16x32_f16(a2, bf, acc[2][bt], 0, 0, 0);
        acc[3][bt] = __builtin_amdgcn_mfma_f32_16x16x32_f16(a3, bf, acc[3][bt], 0, 0, 0);
      }
    }

    if (hn) {
      uint4 v;
      v.x = CMB1(x, r0, r1, r2, r3);
      v.y = CMB1(y, r0, r1, r2, r3);
      v.z = CMB1(z, r0, r1, r2, r3);
      v.w = CMB1(w, r0, r1, r2, r3);
      *(uint4*)(&Bs[j & 1][spx * 20 + qq * 4]) = v;
    }
    __syncthreads();
  }

  // --- epilogue: stores + GN partials ---
  const int colb = lane & 15, prow = (lane >> 4) * 4;
#pragma unroll
  for (int tt = 0; tt < 4; ++tt) {
    float s1 = 0.f, s2 = 0.f;
#pragma unroll
    for (int bt = 0; bt < 4; ++bt) {
      const int jj = bt * 16 + colb;
      const int row = ty * 8 + (jj >> 3), col = tx * 8 + (jj & 7);
      const f32x4 a = acc[tt][bt];
      if (row < HH && col < WW) {
        float* op = out + ((size_t)(n * COUTC + wv * 64 + tt * 16 + prow)) * HW +
                    row * WW + col;
        op[0] = a[0];
        op[HW] = a[1];
        op[2 * HW] = a[2];
        op[3 * HW] = a[3];
      }
      s1 += a[0] + a[1] + a[2] + a[3];
      s2 += a[0] * a[0] + a[1] * a[1] + a[2] * a[2] + a[3] * a[3];
    }
    gr1[wv][tt][lane] = s1;
    gr2[wv][tt][lane] = s2;
  }
  __syncthreads();
  if (tid < 32) {
    const int wv2 = tid >> 3, tt2 = (tid >> 1) & 3, h = tid & 1;
    float a1 = 0.f, a2 = 0.f;
#pragma unroll 8
    for (int i = 0; i < 32; ++i) {
      a1 += gr1[wv2][tt2][h * 32 + i];
      a2 += gr2[wv2][tt2][h * 32 + i];
    }
    float* pp = part + (((size_t)n * NT2 + rem) * GG + tid) * 2;
    pp[0] = a1;
    pp[1] = a2;
  }
}

// ---------------------------------------------------------------------------
// k3: reduce partials -> per (n,g) mean & rsigma
// ---------------------------------------------------------------------------
__global__ void __launch_bounds__(64) k3_stats(const float* __restrict__ part,
                                               float* __restrict__ stats) {
  const int b = blockIdx.x;                // 0..127
  const int n = b >> 5, g = b & 31;
  double s = 0.0, q = 0.0;
  for (int i = threadIdx.x; i < NT2; i += 64) {
    const float* pp = part + (((size_t)n * NT2 + i) * GG + g) * 2;
    s += pp[0];
    q += pp[1];
  }
#pragma unroll
  for (int off = 32; off > 0; off >>= 1) {
    s += __shfl_down(s, off);
    q += __shfl_down(q, off);
  }
  if (threadIdx.x == 0) {
    const double cnt = 8.0 * (double)HW;   // 80000 elems per group
    const double mean = s / cnt;
    const double var = q / cnt - mean * mean;
    stats[b * 2 + 0] = (float)mean;
    stats[b * 2 + 1] = (float)(1.0 / sqrt(var + (double)EPSF));
  }
}

// ---------------------------------------------------------------------------
// k4: in-place GroupNorm affine + ReLU on d_out
// ---------------------------------------------------------------------------
__global__ void __launch_bounds__(256) k4_norm(float* __restrict__ out,
                                               const float* __restrict__ stats,
                                               const float* __restrict__ gw,
                                               const float* __restrict__ gb) {
  const size_t i4 = (size_t)blockIdx.x * 256 + threadIdx.x;  // grid=10000 exact
  const size_t idx = i4 * 4;
  const int n = (int)(idx / ((size_t)COUTC * HW));
  const int r = (int)(idx % ((size_t)COUTC * HW));
  const int o = r / HW;
  const int g = o >> 3;
  const float mean = stats[(n * GG + g) * 2 + 0];
  const float rs = stats[(n * GG + g) * 2 + 1];
  const float sc = rs * gw[o];
  const float sh = gb[o] - mean * sc;
  float4 v = *(float4*)(out + idx);
  v.x = fmaxf(fmaf(v.x, sc, sh), 0.f);
  v.y = fmaxf(fmaf(v.y, sc, sh), 0.f);
  v.z = fmaxf(fmaf(v.z, sc, sh), 0.f);
  v.w = fmaxf(fmaf(v.w, sc, sh), 0.f);
  *(float4*)(out + idx) = v;
}

// ---------------------------------------------------------------------------
extern "C" void kernel_launch(void* const* d_in, const int* in_sizes, int n_in,
                              void* d_out, int out_size, void* d_ws, size_t ws_size,
                              hipStream_t stream) {
  const float* x    = (const float*)d_in[0];
  const float* w_tm = (const float*)d_in[1];
  const float* b_tm = (const float*)d_in[2];
  const float* w_tr = (const float*)d_in[3];
  const float* b_tr = (const float*)d_in[4];
  const float* w_def = (const float*)d_in[5];
  const float* gn_w = (const float*)d_in[6];
  const float* gn_b = (const float*)d_in[7];
  float* out = (float*)d_out;
  float* ws = (float*)d_ws;

  float* posy  = ws;                                     // 360000 f32
  float* posx  = ws + 360000;                            // 360000 f32
  _Float16* wfrag = (_Float16*)(ws + 720000);            // 589824 fp16 = 294912 f32
  _Float16* xh = (_Float16*)(ws + 720000 + 294912);      // 10.24M fp16 = 5.12M f32
  float* part  = ws + 720000 + 294912 + 5120000;         // 4*169*32*2 = 43264 f32
  float* stats = part + 43264;                           // 256 f32
  // total ~24.9 MB of ws

  hipLaunchKernelGGL(k0_wfrag, dim3(2304), dim3(256), 0, stream, w_def, wfrag);
  hipLaunchKernelGGL(kt_nhwc, dim3(2512), dim3(256), 0, stream, x, xh);
  hipLaunchKernelGGL(k1_offsets, dim3(625), dim3(256), 0, stream,
                     x, w_tm, b_tm, w_tr, b_tr, posy, posx);
  hipLaunchKernelGGL(k2_deform, dim3(NBAT * NT2), dim3(256), 0, stream,
                     xh, wfrag, posy, posx, out, part);
  hipLaunchKernelGGL(k3_stats, dim3(NBAT * GG), dim3(64), 0, stream, part, stats);
  hipLaunchKernelGGL(k4_norm, dim3(10000), dim3(256), 0, stream,
                     out, stats, gn_w, gn_b);
}

// Round 4
// 231.065 us; speedup vs baseline: 12.2001x; 1.0827x over previous
//
#include <hip/hip_runtime.h>
#include <math.h>

#define C_IN  256
#define HH    100
#define WW    100
#define HW    10000
#define NBAT  4
#define COUTC 256
#define K9    9
#define GG    32
#define TILES 13           // 13x13 tiles of 8x8 pixels per image
#define NT2   169
#define EPSF  1e-5f

typedef _Float16 f16x8 __attribute__((ext_vector_type(8)));
typedef _Float16 h2v   __attribute__((ext_vector_type(2)));
typedef float    f32x4 __attribute__((ext_vector_type(4)));

// ---------------------------------------------------------------------------
// k0: A-fragment-ordered fp16 deform weights.
// chunk q = tap*8 + cg; Wfrag[q][ot][lane][j]: o=ot*16+(lane&15),
// c=cg*32+(lane>>4)*8+j
// ---------------------------------------------------------------------------
__global__ void __launch_bounds__(256) k0_wfrag(const float* __restrict__ wd,
                                                _Float16* __restrict__ wf) {
  const int i = blockIdx.x * 256 + threadIdx.x;   // < 72*16*64*8 = 589824
  const int j  = i & 7;
  const int l  = (i >> 3) & 63;
  const int ot = (i >> 9) & 15;
  const int q  = i >> 13;
  const int tap = q >> 3, cg = q & 7;
  const int o = ot * 16 + (l & 15);
  const int c = cg * 32 + (l >> 4) * 8 + j;
  wf[i] = (_Float16)wd[((size_t)o * C_IN + c) * K9 + tap];
}

// ---------------------------------------------------------------------------
// k0b: A-fragment fp16 offset-conv weights, 16 couts (rows 6..15 zero).
// wf6[q][lane][j]: o=lane&15 (0..3 w_tm, 4..5 w_tr), c=cg*32+(lane>>4)*8+j
// ---------------------------------------------------------------------------
__global__ void __launch_bounds__(256) k0b_wfrag6(const float* __restrict__ w_tm,
                                                  const float* __restrict__ w_tr,
                                                  _Float16* __restrict__ wf) {
  const int i = blockIdx.x * 256 + threadIdx.x;   // < 72*64*8 = 36864
  const int j = i & 7, l = (i >> 3) & 63, q = i >> 9;
  const int tap = q >> 3, cg = q & 7;
  const int o = l & 15;
  const int c = cg * 32 + (l >> 4) * 8 + j;
  float v = 0.f;
  if (o < 4)      v = w_tm[((size_t)o * C_IN + c) * K9 + tap];
  else if (o < 6) v = w_tr[((size_t)(o - 4) * C_IN + c) * K9 + tap];
  wf[i] = (_Float16)v;
}

// ---------------------------------------------------------------------------
// kt: transpose x (N,C,H,W) f32 -> xh (N,H,W,C) fp16
// ---------------------------------------------------------------------------
__global__ void __launch_bounds__(256) kt_nhwc(const float* __restrict__ x,
                                               _Float16* __restrict__ xh) {
  __shared__ float T[64][65];
  const int b = blockIdx.x;                 // 4n * 4cg * 157 = 2512
  const int n = b / (4 * 157);
  const int r = b % (4 * 157);
  const int cg = r / 157, tile = r % 157;
  const int pbase = tile * 64, c0 = cg * 64;
  const int tid = threadIdx.x, lane = tid & 63, wv = tid >> 6;

#pragma unroll 4
  for (int i = 0; i < 16; ++i) {
    const int c = c0 + wv * 16 + i;
    const int pix = pbase + lane;
    T[wv * 16 + i][lane] = (pix < HW) ? x[((size_t)n * C_IN + c) * HW + pix] : 0.f;
  }
  __syncthreads();

  const int cl = tid & 15;
#pragma unroll
  for (int j = 0; j < 4; ++j) {
    const int pxl = (tid >> 4) + j * 16;
    const int pix = pbase + pxl;
    if (pix < HW) {
      const float v0 = T[cl * 4 + 0][pxl], v1 = T[cl * 4 + 1][pxl];
      const float v2 = T[cl * 4 + 2][pxl], v3 = T[cl * 4 + 3][pxl];
      uint2 pk;
      h2v a = {(_Float16)v0, (_Float16)v1};
      h2v bq = {(_Float16)v2, (_Float16)v3};
      pk.x = __builtin_bit_cast(unsigned, a);
      pk.y = __builtin_bit_cast(unsigned, bq);
      *(uint2*)(xh + ((size_t)n * HW + pix) * C_IN + c0 + cl * 4) = pk;
    }
  }
}

// --- shared helpers -----------------------------------------------------

#define RAW_BARRIER()                                                         \
  asm volatile("s_waitcnt lgkmcnt(0)" ::: "memory");                          \
  __builtin_amdgcn_sched_barrier(0);                                          \
  __builtin_amdgcn_s_barrier();                                               \
  __builtin_amdgcn_sched_barrier(0);

#define CMBC(r0c, r1c, r2c, r3c, W0, W1, W2, W3)                              \
  __builtin_bit_cast(unsigned,                                                \
      (h2v)(W0 * __builtin_bit_cast(h2v, r0c) +                               \
            W1 * __builtin_bit_cast(h2v, r1c) +                               \
            W2 * __builtin_bit_cast(h2v, r2c) +                               \
            W3 * __builtin_bit_cast(h2v, r3c)))

// ---------------------------------------------------------------------------
// k1: offset conv as padded MFMA GEMM (16 couts, 10 zero). Block = 256 px,
// 4 waves (wave: 16 couts x 64 px). Same write-late pipeline as k2.
// Epilogue: transpose acc via LDS -> positions posy/posx.
// ---------------------------------------------------------------------------
__global__ void __launch_bounds__(256) k1_off(
    const _Float16* __restrict__ xh, const _Float16* __restrict__ wf6,
    const float* __restrict__ b_tm, const float* __restrict__ b_tr,
    float* __restrict__ posy, float* __restrict__ posx) {
  const int b = blockIdx.x;                 // 4*40 = 160
  const int n = b / 40, pb = (b % 40) * 256;
  const int tid = threadIdx.x, lane = tid & 63, wv = tid >> 6;

  __shared__ __align__(16) char LS[2 * 256 * 80];   // 40 KB (aliased by T later)

  const int pix = pb + tid;
  const bool valid = pix < HW;
  const int pc = valid ? pix : 0;
  const int h = pc / WW, w = pc % WW;
  const char* xbase = (const char*)(xh + (size_t)n * HW * C_IN);

  int nbA, nbB; bool vA, vB;
#define NBR(T_, NB, V)                                                        \
  {                                                                           \
    const int y = h + (T_) / 3 - 1, xx = w + (T_) % 3 - 1;                    \
    V = valid && ((unsigned)y < (unsigned)HH) && ((unsigned)xx < (unsigned)WW);\
    NB = (V ? (y * WW + xx) : 0) * 512;                                       \
  }
  NBR(0, nbA, vA)
  nbB = nbA; vB = vA;

  uint4 crA0 = *(const uint4*)(xbase + nbA);
  uint4 crA1 = *(const uint4*)(xbase + nbA + 16);
  uint4 crA2 = *(const uint4*)(xbase + nbA + 32);
  uint4 crA3 = *(const uint4*)(xbase + nbA + 48);
  uint4 crB0 = *(const uint4*)(xbase + 64 + nbB);
  uint4 crB1 = *(const uint4*)(xbase + 64 + nbB + 16);
  uint4 crB2 = *(const uint4*)(xbase + 64 + nbB + 32);
  uint4 crB3 = *(const uint4*)(xbase + 64 + nbB + 48);

  f32x4 acc[4];
#pragma unroll
  for (int bt = 0; bt < 4; ++bt) acc[bt] = (f32x4)(0.f);

  char* const swaddr = LS + tid * 80;
  const char* const sraddr = LS + ((wv * 64) + (lane & 15)) * 80 + (lane >> 4) * 16;
  const uint4 z4 = {0u, 0u, 0u, 0u};

#define K1PHASE(P, BUFOFF, CR0, CR1, CR2, CR3, NB, V, BMASK)                  \
  {                                                                           \
    uint4 s0 = V ? CR0 : z4, s1 = V ? CR1 : z4;                               \
    uint4 s2 = V ? CR2 : z4, s3 = V ? CR3 : z4;                               \
    *(uint4*)(swaddr + BUFOFF)      = s0;                                     \
    *(uint4*)(swaddr + BUFOFF + 16) = s1;                                     \
    *(uint4*)(swaddr + BUFOFF + 32) = s2;                                     \
    *(uint4*)(swaddr + BUFOFF + 48) = s3;                                     \
    const _Float16* wfp = wf6 + ((size_t)(P) * 64 + lane) * 8;                \
    f16x8 a0 = *(const f16x8*)(wfp);                                          \
    const int p2 = (P) + 2;                                                   \
    if (p2 < 72) {                                                            \
      if ((p2 & 7) == (BMASK)) NBR(p2 >> 3, NB, V)                            \
      const char* cb = xbase + ((p2 & 7) << 6) + NB;                          \
      CR0 = *(const uint4*)(cb);                                              \
      CR1 = *(const uint4*)(cb + 16);                                         \
      CR2 = *(const uint4*)(cb + 32);                                         \
      CR3 = *(const uint4*)(cb + 48);                                         \
    }                                                                         \
    RAW_BARRIER()                                                             \
    f16x8 b0 = *(const f16x8*)(sraddr + BUFOFF);                              \
    f16x8 b1 = *(const f16x8*)(sraddr + BUFOFF + 1280);                       \
    f16x8 b2 = *(const f16x8*)(sraddr + BUFOFF + 2560);                       \
    f16x8 b3 = *(const f16x8*)(sraddr + BUFOFF + 3840);                       \
    acc[0] = __builtin_amdgcn_mfma_f32_16x16x32_f16(a0, b0, acc[0], 0, 0, 0); \
    acc[1] = __builtin_amdgcn_mfma_f32_16x16x32_f16(a0, b1, acc[1], 0, 0, 0); \
    acc[2] = __builtin_amdgcn_mfma_f32_16x16x32_f16(a0, b2, acc[2], 0, 0, 0); \
    acc[3] = __builtin_amdgcn_mfma_f32_16x16x32_f16(a0, b3, acc[3], 0, 0, 0); \
  }

  for (int i = 0; i < 36; ++i) {
    K1PHASE(2 * i,     0,     crA0, crA1, crA2, crA3, nbA, vA, 0)
    K1PHASE(2 * i + 1, 20480, crB0, crB1, crB2, crB3, nbB, vB, 1)
  }
  __syncthreads();

  float* T = (float*)LS;   // [256][17]
#pragma unroll
  for (int bt = 0; bt < 4; ++bt) {
    const int px = wv * 64 + bt * 16 + (lane & 15);
    const int oc = (lane >> 4) * 4;
    T[px * 17 + oc + 0] = acc[bt][0];
    T[px * 17 + oc + 1] = acc[bt][1];
    T[px * 17 + oc + 2] = acc[bt][2];
    T[px * 17 + oc + 3] = acc[bt][3];
  }
  __syncthreads();

  if (valid) {
    const float A00 = T[tid * 17 + 0] + b_tm[0];
    const float A01 = T[tid * 17 + 1] + b_tm[1];
    const float A10 = T[tid * 17 + 2] + b_tm[2];
    const float A11 = T[tid * 17 + 3] + b_tm[3];
    const float t0 = T[tid * 17 + 4] + b_tr[0];
    const float t1 = T[tid * 17 + 5] + b_tr[1];
    const float fh = (float)h, fw = (float)w;
#pragma unroll
    for (int k = 0; k < 9; ++k) {
      const float ry = (float)(k / 3 - 1);
      const float rx = (float)(k % 3 - 1);
      posy[((size_t)n * K9 + k) * HW + pix] = fh + t0 + A00 * ry + A01 * rx;
      posx[((size_t)n * K9 + k) * HW + pix] = fw + t1 + A10 * ry + A11 * rx;
    }
  }
}

// ---------------------------------------------------------------------------
// k2: deformable conv, fp16 MFMA GEMM, write-late pipelined phases.
// Block: 8x8 px (64) x 256 couts, 4 waves (wave: 64 couts x 64 px).
// 72 phases of K=32 (tap-major). Corner loads 2 phases ahead (parity A/B),
// raw lgkm-only barrier -> global loads stay in flight across barriers.
// ---------------------------------------------------------------------------
__global__ void __launch_bounds__(256, 2) k2_deform(
    const _Float16* __restrict__ xh, const _Float16* __restrict__ wfrag,
    const float* __restrict__ posy, const float* __restrict__ posx,
    float* __restrict__ out, float* __restrict__ part) {
  const int b = blockIdx.x;                 // grid = 4*169 = 676
  const int n = b / NT2, rem = b % NT2;
  const int ty = rem / TILES, tx = rem % TILES;
  const int tid = threadIdx.x;
  const int lane = tid & 63, wv = tid >> 6;

  __shared__ __align__(16) unsigned int Bs[2][1280];   // [buf][64px x 80B]
  __shared__ float gr1[4][4][64];
  __shared__ float gr2[4][4][64];

  const int spx = tid & 63;          // staging pixel
  const int sch = tid >> 6;          // staging ch-octet (8 of 32)
  const int srow = ty * 8 + (spx >> 3), scol = tx * 8 + (spx & 7);
  const bool pv = (srow < HH) && (scol < WW);
  const int mypix = srow * WW + scol;
  const int mpa = pv ? mypix : 0;

  const char* xbase = (const char*)(xh + (size_t)n * HW * C_IN);

  float pyt, pxt, pyn, pxn;
  {
    float a = posy[(size_t)(n * K9 + 0) * HW + mpa];
    float c = posx[(size_t)(n * K9 + 0) * HW + mpa];
    pyt = pv ? a : -1e4f; pxt = pv ? c : -1e4f;
    float a1 = posy[(size_t)(n * K9 + 1) * HW + mpa];
    float c1 = posx[(size_t)(n * K9 + 1) * HW + mpa];
    pyn = pv ? a1 : -1e4f; pxn = pv ? c1 : -1e4f;
  }

  int caA0, caA1, caA2, caA3, caB0, caB1, caB2, caB3;
  h2v cwA0, cwA1, cwA2, cwA3, cwB0, cwB1, cwB2, cwB3;

#define CORNCALC(CA0, CA1, CA2, CA3, W0, W1, W2, W3)                          \
  {                                                                           \
    const float y0f = floorf(pyt), x0f = floorf(pxt);                         \
    const float wy = pyt - y0f, wx = pxt - x0f;                               \
    const int iy0 = (int)y0f, ix0 = (int)x0f;                                 \
    const bool vy0 = ((unsigned)iy0 < (unsigned)HH);                          \
    const bool vy1 = ((unsigned)(iy0 + 1) < (unsigned)HH);                    \
    const bool vx0 = ((unsigned)ix0 < (unsigned)WW);                          \
    const bool vx1 = ((unsigned)(ix0 + 1) < (unsigned)WW);                    \
    const bool v0 = vy0 && vx0, v1 = vy0 && vx1;                              \
    const bool v2 = vy1 && vx0, v3 = vy1 && vx1;                              \
    const int bo = sch * 16;                                                  \
    CA0 = (v0 ? (iy0 * WW + ix0) * 512 : 0) + bo;                             \
    CA1 = (v1 ? (iy0 * WW + ix0 + 1) * 512 : 0) + bo;                         \
    CA2 = (v2 ? ((iy0 + 1) * WW + ix0) * 512 : 0) + bo;                       \
    CA3 = (v3 ? ((iy0 + 1) * WW + ix0 + 1) * 512 : 0) + bo;                   \
    const float g0 = v0 ? (1.f - wy) * (1.f - wx) : 0.f;                      \
    const float g1 = v1 ? (1.f - wy) * wx : 0.f;                              \
    const float g2 = v2 ? wy * (1.f - wx) : 0.f;                              \
    const float g3 = v3 ? wy * wx : 0.f;                                      \
    const _Float16 h0 = (_Float16)g0, h1 = (_Float16)g1;                      \
    const _Float16 hh2 = (_Float16)g2, h3 = (_Float16)g3;                     \
    W0 = (h2v){h0, h0}; W1 = (h2v){h1, h1};                                   \
    W2 = (h2v){hh2, hh2}; W3 = (h2v){h3, h3};                                 \
  }

  CORNCALC(caA0, caA1, caA2, caA3, cwA0, cwA1, cwA2, cwA3)
  caB0 = caA0; caB1 = caA1; caB2 = caA2; caB3 = caA3;
  cwB0 = cwA0; cwB1 = cwA1; cwB2 = cwA2; cwB3 = cwA3;

  uint4 crA0 = *(const uint4*)(xbase + caA0);
  uint4 crA1 = *(const uint4*)(xbase + caA1);
  uint4 crA2 = *(const uint4*)(xbase + caA2);
  uint4 crA3 = *(const uint4*)(xbase + caA3);
  uint4 crB0 = *(const uint4*)(xbase + 64 + caB0);
  uint4 crB1 = *(const uint4*)(xbase + 64 + caB1);
  uint4 crB2 = *(const uint4*)(xbase + 64 + caB2);
  uint4 crB3 = *(const uint4*)(xbase + 64 + caB3);

  f32x4 acc[4][4];
#pragma unroll
  for (int tt = 0; tt < 4; ++tt)
#pragma unroll
    for (int bt = 0; bt < 4; ++bt) acc[tt][bt] = (f32x4)(0.f);

  char* const swaddr = (char*)&Bs[0][0] + spx * 80 + sch * 16;
  const char* const sraddr = (const char*)&Bs[0][0] + (lane & 15) * 80 + (lane >> 4) * 16;

#define K2PHASE(P, BUFOFF, CR0, CR1, CR2, CR3, CA0, CA1, CA2, CA3,            \
                W0, W1, W2, W3, ISEVEN)                                       \
  {                                                                           \
    uint4 sv;                                                                 \
    sv.x = CMBC(CR0.x, CR1.x, CR2.x, CR3.x, W0, W1, W2, W3);                  \
    sv.y = CMBC(CR0.y, CR1.y, CR2.y, CR3.y, W0, W1, W2, W3);                  \
    sv.z = CMBC(CR0.z, CR1.z, CR2.z, CR3.z, W0, W1, W2, W3);                  \
    sv.w = CMBC(CR0.w, CR1.w, CR2.w, CR3.w, W0, W1, W2, W3);                  \
    *(uint4*)(swaddr + BUFOFF) = sv;                                          \
    const _Float16* wfp = wfrag + (((size_t)(P) * 16 + wv * 4) * 64 + lane) * 8; \
    f16x8 a0 = *(const f16x8*)(wfp);                                          \
    f16x8 a1 = *(const f16x8*)(wfp + 512);                                    \
    f16x8 a2 = *(const f16x8*)(wfp + 1024);                                   \
    f16x8 a3 = *(const f16x8*)(wfp + 1536);                                   \
    const int p2 = (P) + 2;                                                   \
    if (p2 < 72) {                                                            \
      if (ISEVEN) {                                                           \
        if ((p2 & 7) == 0) {                                                  \
          pyt = pyn; pxt = pxn;                                               \
          CORNCALC(CA0, CA1, CA2, CA3, W0, W1, W2, W3)                        \
          const int tn = (p2 >> 3) + 1;                                       \
          if (tn < 9) {                                                       \
            float a = posy[(size_t)(n * K9 + tn) * HW + mpa];                 \
            float c = posx[(size_t)(n * K9 + tn) * HW + mpa];                 \
            pyn = pv ? a : -1e4f; pxn = pv ? c : -1e4f;                       \
          }                                                                   \
        }                                                                     \
      } else {                                                                \
        if ((p2 & 7) == 1) { CORNCALC(CA0, CA1, CA2, CA3, W0, W1, W2, W3) }   \
      }                                                                       \
      const char* cb = xbase + ((p2 & 7) << 6);                               \
      CR0 = *(const uint4*)(cb + CA0);                                        \
      CR1 = *(const uint4*)(cb + CA1);                                        \
      CR2 = *(const uint4*)(cb + CA2);                                        \
      CR3 = *(const uint4*)(cb + CA3);                                        \
    }                                                                         \
    RAW_BARRIER()                                                             \
    f16x8 b0 = *(const f16x8*)(sraddr + BUFOFF);                              \
    f16x8 b1 = *(const f16x8*)(sraddr + BUFOFF + 1280);                       \
    f16x8 b2 = *(const f16x8*)(sraddr + BUFOFF + 2560);                       \
    f16x8 b3 = *(const f16x8*)(sraddr + BUFOFF + 3840);                       \
    acc[0][0] = __builtin_amdgcn_mfma_f32_16x16x32_f16(a0, b0, acc[0][0], 0, 0, 0); \
    acc[0][1] = __builtin_amdgcn_mfma_f32_16x16x32_f16(a0, b1, acc[0][1], 0, 0, 0); \
    acc[0][2] = __builtin_amdgcn_mfma_f32_16x16x32_f16(a0, b2, acc[0][2], 0, 0, 0); \
    acc[0][3] = __builtin_amdgcn_mfma_f32_16x16x32_f16(a0, b3, acc[0][3], 0, 0, 0); \
    acc[1][0] = __builtin_amdgcn_mfma_f32_16x16x32_f16(a1, b0, acc[1][0], 0, 0, 0); \
    acc[1][1] = __builtin_amdgcn_mfma_f32_16x16x32_f16(a1, b1, acc[1][1], 0, 0, 0); \
    acc[1][2] = __builtin_amdgcn_mfma_f32_16x16x32_f16(a1, b2, acc[1][2], 0, 0, 0); \
    acc[1][3] = __builtin_amdgcn_mfma_f32_16x16x32_f16(a1, b3, acc[1][3], 0, 0, 0); \
    acc[2][0] = __builtin_amdgcn_mfma_f32_16x16x32_f16(a2, b0, acc[2][0], 0, 0, 0); \
    acc[2][1] = __builtin_amdgcn_mfma_f32_16x16x32_f16(a2, b1, acc[2][1], 0, 0, 0); \
    acc[2][2] = __builtin_amdgcn_mfma_f32_16x16x32_f16(a2, b2, acc[2][2], 0, 0, 0); \
    acc[2][3] = __builtin_amdgcn_mfma_f32_16x16x32_f16(a2, b3, acc[2][3], 0, 0, 0); \
    acc[3][0] = __builtin_amdgcn_mfma_f32_16x16x32_f16(a3, b0, acc[3][0], 0, 0, 0); \
    acc[3][1] = __builtin_amdgcn_mfma_f32_16x16x32_f16(a3, b1, acc[3][1], 0, 0, 0); \
    acc[3][2] = __builtin_amdgcn_mfma_f32_16x16x32_f16(a3, b2, acc[3][2], 0, 0, 0); \
    acc[3][3] = __builtin_amdgcn_mfma_f32_16x16x32_f16(a3, b3, acc[3][3], 0, 0, 0); \
  }

  for (int i = 0; i < 36; ++i) {
    K2PHASE(2 * i, 0, crA0, crA1, crA2, crA3, caA0, caA1, caA2, caA3,
            cwA0, cwA1, cwA2, cwA3, 1)
    K2PHASE(2 * i + 1, 5120, crB0, crB1, crB2, crB3, caB0, caB1, caB2, caB3,
            cwB0, cwB1, cwB2, cwB3, 0)
  }

  // --- epilogue: stores + GN partials ---
  const int colb = lane & 15, prow = (lane >> 4) * 4;
#pragma unroll
  for (int tt = 0; tt < 4; ++tt) {
    float s1 = 0.f, s2 = 0.f;
#pragma unroll
    for (int bt = 0; bt < 4; ++bt) {
      const int jj = bt * 16 + colb;
      const int row = ty * 8 + (jj >> 3), col = tx * 8 + (jj & 7);
      const f32x4 a = acc[tt][bt];
      if (row < HH && col < WW) {
        float* op = out + ((size_t)(n * COUTC + wv * 64 + tt * 16 + prow)) * HW +
                    row * WW + col;
        op[0] = a[0];
        op[HW] = a[1];
        op[2 * HW] = a[2];
        op[3 * HW] = a[3];
      }
      s1 += a[0] + a[1] + a[2] + a[3];
      s2 += a[0] * a[0] + a[1] * a[1] + a[2] * a[2] + a[3] * a[3];
    }
    gr1[wv][tt][lane] = s1;
    gr2[wv][tt][lane] = s2;
  }
  __syncthreads();
  if (tid < 32) {
    const int wv2 = tid >> 3, tt2 = (tid >> 1) & 3, bit = tid & 1;
    float a1 = 0.f, a2 = 0.f;
#pragma unroll 8
    for (int l = 0; l < 32; ++l) {
      a1 += gr1[wv2][tt2][bit * 32 + l];
      a2 += gr2[wv2][tt2][bit * 32 + l];
    }
    float* pp = part + (((size_t)n * NT2 + rem) * GG + tid) * 2;
    pp[0] = a1;
    pp[1] = a2;
  }
}

// ---------------------------------------------------------------------------
// k3: reduce partials -> per (n,g) mean & rsigma
// ---------------------------------------------------------------------------
__global__ void __launch_bounds__(64) k3_stats(const float* __restrict__ part,
                                               float* __restrict__ stats) {
  const int b = blockIdx.x;                // 0..127
  const int n = b >> 5, g = b & 31;
  double s = 0.0, q = 0.0;
  for (int i = threadIdx.x; i < NT2; i += 64) {
    const float* pp = part + (((size_t)n * NT2 + i) * GG + g) * 2;
    s += pp[0];
    q += pp[1];
  }
#pragma unroll
  for (int off = 32; off > 0; off >>= 1) {
    s += __shfl_down(s, off);
    q += __shfl_down(q, off);
  }
  if (threadIdx.x == 0) {
    const double cnt = 8.0 * (double)HW;
    const double mean = s / cnt;
    const double var = q / cnt - mean * mean;
    stats[b * 2 + 0] = (float)mean;
    stats[b * 2 + 1] = (float)(1.0 / sqrt(var + (double)EPSF));
  }
}

// ---------------------------------------------------------------------------
// k4: in-place GroupNorm affine + ReLU on d_out
// ---------------------------------------------------------------------------
__global__ void __launch_bounds__(256) k4_norm(float* __restrict__ out,
                                               const float* __restrict__ stats,
                                               const float* __restrict__ gw,
                                               const float* __restrict__ gb) {
  const size_t i4 = (size_t)blockIdx.x * 256 + threadIdx.x;
  const size_t idx = i4 * 4;
  const int n = (int)(idx / ((size_t)COUTC * HW));
  const int r = (int)(idx % ((size_t)COUTC * HW));
  const int o = r / HW;
  const int g = o >> 3;
  const float mean = stats[(n * GG + g) * 2 + 0];
  const float rs = stats[(n * GG + g) * 2 + 1];
  const float sc = rs * gw[o];
  const float sh = gb[o] - mean * sc;
  float4 v = *(float4*)(out + idx);
  v.x = fmaxf(fmaf(v.x, sc, sh), 0.f);
  v.y = fmaxf(fmaf(v.y, sc, sh), 0.f);
  v.z = fmaxf(fmaf(v.z, sc, sh), 0.f);
  v.w = fmaxf(fmaf(v.w, sc, sh), 0.f);
  *(float4*)(out + idx) = v;
}

// ---------------------------------------------------------------------------
extern "C" void kernel_launch(void* const* d_in, const int* in_sizes, int n_in,
                              void* d_out, int out_size, void* d_ws, size_t ws_size,
                              hipStream_t stream) {
  const float* x    = (const float*)d_in[0];
  const float* w_tm = (const float*)d_in[1];
  const float* b_tm = (const float*)d_in[2];
  const float* w_tr = (const float*)d_in[3];
  const float* b_tr = (const float*)d_in[4];
  const float* w_def = (const float*)d_in[5];
  const float* gn_w = (const float*)d_in[6];
  const float* gn_b = (const float*)d_in[7];
  float* out = (float*)d_out;
  float* ws = (float*)d_ws;

  float* posy  = ws;                                     // 360000 f32
  float* posx  = ws + 360000;                            // 360000 f32
  _Float16* wfrag = (_Float16*)(ws + 720000);            // 589824 fp16
  _Float16* wf6   = (_Float16*)(ws + 1014912);           // 36864 fp16
  _Float16* xh    = (_Float16*)(ws + 1033344);           // 10.24M fp16
  float* part  = ws + 6153344;                           // 43264 f32
  float* stats = ws + 6196608;                           // 256 f32

  hipLaunchKernelGGL(k0_wfrag, dim3(2304), dim3(256), 0, stream, w_def, wfrag);
  hipLaunchKernelGGL(k0b_wfrag6, dim3(144), dim3(256), 0, stream, w_tm, w_tr, wf6);
  hipLaunchKernelGGL(kt_nhwc, dim3(2512), dim3(256), 0, stream, x, xh);
  hipLaunchKernelGGL(k1_off, dim3(160), dim3(256), 0, stream,
                     xh, wf6, b_tm, b_tr, posy, posx);
  hipLaunchKernelGGL(k2_deform, dim3(NBAT * NT2), dim3(256), 0, stream,
                     xh, wfrag, posy, posx, out, part);
  hipLaunchKernelGGL(k3_stats, dim3(NBAT * GG), dim3(64), 0, stream, part, stats);
  hipLaunchKernelGGL(k4_norm, dim3(10000), dim3(256), 0, stream,
                     out, stats, gn_w, gn_b);
}

// Round 5
// 197.930 us; speedup vs baseline: 14.2424x; 1.1674x over previous
//
#include <hip/hip_runtime.h>
#include <math.h>

#define C_IN  256
#define HH    100
#define WW    100
#define HW    10000
#define NBAT  4
#define COUTC 256
#define K9    9
#define GG    32
#define NT2   325         // per-image tiles: 25 (rows of 4) x 13 (cols of 8)
#define TXN   13
#define EPSF  1e-5f

typedef _Float16 f16x8 __attribute__((ext_vector_type(8)));
typedef _Float16 h2v   __attribute__((ext_vector_type(2)));
typedef float    f32x4 __attribute__((ext_vector_type(4)));

// ---------------------------------------------------------------------------
// k0: A-fragment-ordered fp16 deform weights.
// chunk q = tap*8 + cg; Wfrag[q][ot][lane][j]: o=ot*16+(lane&15),
// c=cg*32+(lane>>4)*8+j
// ---------------------------------------------------------------------------
__global__ void __launch_bounds__(256) k0_wfrag(const float* __restrict__ wd,
                                                _Float16* __restrict__ wf) {
  const int i = blockIdx.x * 256 + threadIdx.x;   // < 72*16*64*8 = 589824
  const int j  = i & 7;
  const int l  = (i >> 3) & 63;
  const int ot = (i >> 9) & 15;
  const int q  = i >> 13;
  const int tap = q >> 3, cg = q & 7;
  const int o = ot * 16 + (l & 15);
  const int c = cg * 32 + (l >> 4) * 8 + j;
  wf[i] = (_Float16)wd[((size_t)o * C_IN + c) * K9 + tap];
}

// ---------------------------------------------------------------------------
// k0b: A-fragment fp16 offset-conv weights, 16 couts (rows 6..15 zero).
// ---------------------------------------------------------------------------
__global__ void __launch_bounds__(256) k0b_wfrag6(const float* __restrict__ w_tm,
                                                  const float* __restrict__ w_tr,
                                                  _Float16* __restrict__ wf) {
  const int i = blockIdx.x * 256 + threadIdx.x;   // < 72*64*8 = 36864
  const int j = i & 7, l = (i >> 3) & 63, q = i >> 9;
  const int tap = q >> 3, cg = q & 7;
  const int o = l & 15;
  const int c = cg * 32 + (l >> 4) * 8 + j;
  float v = 0.f;
  if (o < 4)      v = w_tm[((size_t)o * C_IN + c) * K9 + tap];
  else if (o < 6) v = w_tr[((size_t)(o - 4) * C_IN + c) * K9 + tap];
  wf[i] = (_Float16)v;
}

// ---------------------------------------------------------------------------
// kt: transpose x (N,C,H,W) f32 -> xh (N,H,W,C) fp16
// ---------------------------------------------------------------------------
__global__ void __launch_bounds__(256) kt_nhwc(const float* __restrict__ x,
                                               _Float16* __restrict__ xh) {
  __shared__ float T[64][65];
  const int b = blockIdx.x;                 // 4n * 4cg * 157 = 2512
  const int n = b / (4 * 157);
  const int r = b % (4 * 157);
  const int cg = r / 157, tile = r % 157;
  const int pbase = tile * 64, c0 = cg * 64;
  const int tid = threadIdx.x, lane = tid & 63, wv = tid >> 6;

#pragma unroll 4
  for (int i = 0; i < 16; ++i) {
    const int c = c0 + wv * 16 + i;
    const int pix = pbase + lane;
    T[wv * 16 + i][lane] = (pix < HW) ? x[((size_t)n * C_IN + c) * HW + pix] : 0.f;
  }
  __syncthreads();

  const int cl = tid & 15;
#pragma unroll
  for (int j = 0; j < 4; ++j) {
    const int pxl = (tid >> 4) + j * 16;
    const int pix = pbase + pxl;
    if (pix < HW) {
      const float v0 = T[cl * 4 + 0][pxl], v1 = T[cl * 4 + 1][pxl];
      const float v2 = T[cl * 4 + 2][pxl], v3 = T[cl * 4 + 3][pxl];
      uint2 pk;
      h2v a = {(_Float16)v0, (_Float16)v1};
      h2v bq = {(_Float16)v2, (_Float16)v3};
      pk.x = __builtin_bit_cast(unsigned, a);
      pk.y = __builtin_bit_cast(unsigned, bq);
      *(uint2*)(xh + ((size_t)n * HW + pix) * C_IN + c0 + cl * 4) = pk;
    }
  }
}

#define RAW_BARRIER()                                                         \
  asm volatile("s_waitcnt lgkmcnt(0)" ::: "memory");                          \
  __builtin_amdgcn_sched_barrier(0);                                          \
  __builtin_amdgcn_s_barrier();                                               \
  __builtin_amdgcn_sched_barrier(0);

// ---------------------------------------------------------------------------
// k1: offset conv, wave-independent (no LDS, no barriers in main loop).
// Wave owns 16 px; lane: px=ps+(l&15), k-octet=(l>>4). Gathered 16B per lane
// IS the B fragment. A (wf6) 2-deep reg prefetch; B 4-deep reg queue.
// ---------------------------------------------------------------------------
__global__ void __launch_bounds__(256) k1_off(
    const _Float16* __restrict__ xh, const _Float16* __restrict__ wf6,
    const float* __restrict__ b_tm, const float* __restrict__ b_tr,
    float* __restrict__ posy, float* __restrict__ posx) {
  const int tid = threadIdx.x, lane = tid & 63, wv = tid >> 6;
  const int s = blockIdx.x * 4 + wv;        // 0..2499, grid 625
  const int n = s / 625, strip = s % 625;
  const int ps = strip * 16;
  const int px = ps + (lane & 15);
  const int h = px / WW, w = px % WW;
  const char* xbase = (const char*)(xh + (size_t)n * HW * C_IN) + (lane >> 4) * 16;

  int nbA, nbB; bool vA, vB;
#define K1NB(T_, NB, V)                                                       \
  { const int y = h + (T_) / 3 - 1, xx = w + (T_) % 3 - 1;                    \
    V = ((unsigned)y < (unsigned)HH) && ((unsigned)xx < (unsigned)WW);        \
    NB = (V ? (y * WW + xx) : 0) * 512; }

  uint4 q0, q1, q2, q3;
  K1NB(0, nbA, vA)
  nbB = nbA; vB = vA;
  q0 = *(const uint4*)(xbase + nbA + 0 * 64);
  q1 = *(const uint4*)(xbase + nbA + 1 * 64);
  q2 = *(const uint4*)(xbase + nbA + 2 * 64);
  q3 = *(const uint4*)(xbase + nbA + 3 * 64);
  f16x8 afA = *(const f16x8*)(wf6 + (size_t)0 * 512 + lane * 8);
  f16x8 afB = *(const f16x8*)(wf6 + (size_t)1 * 512 + lane * 8);

  f32x4 acc = (f32x4)(0.f);
  const uint4 z4 = {0u, 0u, 0u, 0u};

#define K1SUB(CG, Q, AF)                                                      \
  {                                                                           \
    const int p = t * 8 + (CG);                                               \
    uint4 bq = vA ? Q : z4;                                                   \
    f16x8 bf = __builtin_bit_cast(f16x8, bq);                                 \
    if ((CG) == 2) { K1NB((t < 8 ? t + 1 : 8), nbB, vB) }                     \
    if ((CG) < 4) { Q = *(const uint4*)(xbase + nbA + ((CG) + 4) * 64); }     \
    else if (t < 8) { Q = *(const uint4*)(xbase + nbB + ((CG) - 4) * 64); }   \
    acc = __builtin_amdgcn_mfma_f32_16x16x32_f16(AF, bf, acc, 0, 0, 0);       \
    if ((CG) < 6 || t < 8)                                                    \
      AF = *(const f16x8*)(wf6 + (size_t)(p + 2) * 512 + lane * 8);           \
  }

  for (int t = 0; t < 9; ++t) {
    K1SUB(0, q0, afA) K1SUB(1, q1, afB) K1SUB(2, q2, afA) K1SUB(3, q3, afB)
    K1SUB(4, q0, afA) K1SUB(5, q1, afB) K1SUB(6, q2, afA) K1SUB(7, q3, afB)
    nbA = nbB; vA = vB;
  }

  // epilogue: lane<16 holds couts 0..3 (A row (lane>>4)*4+r), lane+16 holds 4..7
  const float t0v = __shfl(acc[0], (lane & 15) + 16);
  const float t1v = __shfl(acc[1], (lane & 15) + 16);
  if (lane < 16) {
    const float A00 = acc[0] + b_tm[0], A01 = acc[1] + b_tm[1];
    const float A10 = acc[2] + b_tm[2], A11 = acc[3] + b_tm[3];
    const float t0 = t0v + b_tr[0], t1 = t1v + b_tr[1];
    const float fh = (float)h, fw = (float)w;
#pragma unroll
    for (int k = 0; k < 9; ++k) {
      const float ry = (float)(k / 3 - 1);
      const float rx = (float)(k % 3 - 1);
      posy[((size_t)n * K9 + k) * HW + px] = fh + t0 + A00 * ry + A01 * rx;
      posx[((size_t)n * K9 + k) * HW + px] = fw + t1 + A10 * ry + A11 * rx;
    }
  }
}

// ---------------------------------------------------------------------------
// k2: deformable conv fp16 MFMA GEMM. Block: 4x8 px tile (32 px) x 256 couts,
// 4 waves. 72 phases (tap-major K=32). Corner addr/weight tables in LDS;
// 4-deep corner register queue; A-frags 2-deep register double-buffer
// reloaded AFTER the MFMAs so compiler vmcnt(N) waits keep corner prefetch
// in flight. lgkm-only barrier.
// ---------------------------------------------------------------------------
__global__ void __launch_bounds__(256, 3) k2_deform(
    const _Float16* __restrict__ xh, const _Float16* __restrict__ wfrag,
    const float* __restrict__ posy, const float* __restrict__ posx,
    float* __restrict__ out, float* __restrict__ part) {
  const int b = blockIdx.x;                 // grid = 4*325 = 1300
  const int n = b / NT2, rem = b % NT2;
  const int ty = rem / TXN, tx = rem % TXN;
  const int tid = threadIdx.x;
  const int lane = tid & 63, wv = tid >> 6;

  __shared__ __align__(16) unsigned int Bs[2 * 640];     // 2 x (32px x 80B)
  __shared__ __align__(16) unsigned int ctab[288 * 8];   // [tap*32+px][4 addr,4 wt]
  __shared__ float gr1[4][4][64], gr2[4][4][64];

  // --- build corner tables: 288 = 9 taps x 32 px ---
  for (int s = tid; s < 288; s += 256) {
    const int tap = s >> 5, j = s & 31;
    const int row = ty * 4 + (j >> 3), col = tx * 8 + (j & 7);
    const bool pvv = (col < WW);            // rows always < 100
    const int mpa = pvv ? (row * WW + col) : 0;
    float ys = posy[((size_t)n * K9 + tap) * HW + mpa];
    float xs = posx[((size_t)n * K9 + tap) * HW + mpa];
    if (!pvv) { ys = -1e4f; xs = -1e4f; }
    const float y0f = floorf(ys), x0f = floorf(xs);
    const float wy = ys - y0f, wx = xs - x0f;
    const int iy0 = (int)y0f, ix0 = (int)x0f;
    const bool vy0 = ((unsigned)iy0 < (unsigned)HH);
    const bool vy1 = ((unsigned)(iy0 + 1) < (unsigned)HH);
    const bool vx0 = ((unsigned)ix0 < (unsigned)WW);
    const bool vx1 = ((unsigned)(ix0 + 1) < (unsigned)WW);
    const bool v0 = vy0 && vx0, v1 = vy0 && vx1;
    const bool v2 = vy1 && vx0, v3 = vy1 && vx1;
    uint4 oa, wa;
    oa.x = (v0 ? (iy0 * WW + ix0) : 0) * 512u;
    oa.y = (v1 ? (iy0 * WW + ix0 + 1) : 0) * 512u;
    oa.z = (v2 ? ((iy0 + 1) * WW + ix0) : 0) * 512u;
    oa.w = (v3 ? ((iy0 + 1) * WW + ix0 + 1) : 0) * 512u;
    const float g0 = v0 ? (1.f - wy) * (1.f - wx) : 0.f;
    const float g1 = v1 ? (1.f - wy) * wx : 0.f;
    const float g2 = v2 ? wy * (1.f - wx) : 0.f;
    const float g3 = v3 ? wy * wx : 0.f;
    const _Float16 h0 = (_Float16)g0, h1 = (_Float16)g1;
    const _Float16 h2_ = (_Float16)g2, h3 = (_Float16)g3;
    wa.x = __builtin_bit_cast(unsigned, (h2v){h0, h0});
    wa.y = __builtin_bit_cast(unsigned, (h2v){h1, h1});
    wa.z = __builtin_bit_cast(unsigned, (h2v){h2_, h2_});
    wa.w = __builtin_bit_cast(unsigned, (h2v){h3, h3});
    uint4* cp = (uint4*)&ctab[s * 8];
    cp[0] = oa;
    cp[1] = wa;
  }
  __syncthreads();

  const int spx = tid >> 3, sc8 = tid & 7;   // staging: px 0..31, ch-quad 0..7
  const char* xbase = (const char*)(xh + (size_t)n * HW * C_IN);

  uint4 Ocur = *(const uint4*)&ctab[spx * 8];        // tap 0 addrs
  uint4 Wcmb = *(const uint4*)&ctab[spx * 8 + 4];    // tap 0 weights
  uint4 Onew, Wnew;

  uint2 q0[4], q1[4], q2[4], q3[4];
#define ISSUEQ(QA, O, CHOFF)                                                  \
  QA[0] = *(const uint2*)(xbase + (O).x + (CHOFF) + sc8 * 8);                 \
  QA[1] = *(const uint2*)(xbase + (O).y + (CHOFF) + sc8 * 8);                 \
  QA[2] = *(const uint2*)(xbase + (O).z + (CHOFF) + sc8 * 8);                 \
  QA[3] = *(const uint2*)(xbase + (O).w + (CHOFF) + sc8 * 8);

  ISSUEQ(q0, Ocur, 0)
  ISSUEQ(q1, Ocur, 64)
  ISSUEQ(q2, Ocur, 128)
  ISSUEQ(q3, Ocur, 192)

  f16x8 aA0, aA1, aA2, aA3, aB0, aB1, aB2, aB3;
  {
    const _Float16* w0 = wfrag + ((size_t)(0 * 16 + wv * 4) * 64 + lane) * 8;
    aA0 = *(const f16x8*)(w0);
    aA1 = *(const f16x8*)(w0 + 512);
    aA2 = *(const f16x8*)(w0 + 1024);
    aA3 = *(const f16x8*)(w0 + 1536);
    const _Float16* w1 = wfrag + ((size_t)(1 * 16 + wv * 4) * 64 + lane) * 8;
    aB0 = *(const f16x8*)(w1);
    aB1 = *(const f16x8*)(w1 + 512);
    aB2 = *(const f16x8*)(w1 + 1024);
    aB3 = *(const f16x8*)(w1 + 1536);
  }

  f32x4 acc[4][2];
#pragma unroll
  for (int tt = 0; tt < 4; ++tt) {
    acc[tt][0] = (f32x4)(0.f);
    acc[tt][1] = (f32x4)(0.f);
  }

  char* const swaddr = (char*)&Bs[0] + spx * 80 + sc8 * 8;
  const char* const sraddr = (const char*)&Bs[0] + (lane & 15) * 80 + (lane >> 4) * 16;

#define MF(a, bx, t_, b_) \
  acc[t_][b_] = __builtin_amdgcn_mfma_f32_16x16x32_f16(a, bx, acc[t_][b_], 0, 0, 0);

#define SUB(CG, QA, A0_, A1_, A2_, A3_)                                       \
  {                                                                           \
    const int p = t * 8 + (CG);                                               \
    {                                                                         \
      h2v w0 = __builtin_bit_cast(h2v, Wcmb.x), w1 = __builtin_bit_cast(h2v, Wcmb.y); \
      h2v w2 = __builtin_bit_cast(h2v, Wcmb.z), w3 = __builtin_bit_cast(h2v, Wcmb.w); \
      h2v rx = w0 * __builtin_bit_cast(h2v, QA[0].x) + w1 * __builtin_bit_cast(h2v, QA[1].x) \
             + w2 * __builtin_bit_cast(h2v, QA[2].x) + w3 * __builtin_bit_cast(h2v, QA[3].x); \
      h2v ry = w0 * __builtin_bit_cast(h2v, QA[0].y) + w1 * __builtin_bit_cast(h2v, QA[1].y) \
             + w2 * __builtin_bit_cast(h2v, QA[2].y) + w3 * __builtin_bit_cast(h2v, QA[3].y); \
      uint2 sv;                                                               \
      sv.x = __builtin_bit_cast(unsigned, rx);                                \
      sv.y = __builtin_bit_cast(unsigned, ry);                                \
      *(uint2*)(swaddr + ((CG) & 1) * 2560) = sv;                             \
    }                                                                         \
    if ((CG) < 4) { ISSUEQ(QA, Ocur, ((CG) + 4) * 64) }                       \
    else if (t < 8) { ISSUEQ(QA, Onew, ((CG) - 4) * 64) }                     \
    if ((CG) == 2) {                                                          \
      const int tn = (t < 8 ? t + 1 : 8);                                     \
      Onew = *(const uint4*)&ctab[(tn * 32 + spx) * 8];                       \
      Wnew = *(const uint4*)&ctab[(tn * 32 + spx) * 8 + 4];                   \
    }                                                                         \
    RAW_BARRIER()                                                             \
    const char* bb = sraddr + ((CG) & 1) * 2560;                              \
    f16x8 b0 = *(const f16x8*)(bb);                                           \
    f16x8 b1 = *(const f16x8*)(bb + 1280);                                    \
    MF(A0_, b0, 0, 0) MF(A0_, b1, 0, 1)                                       \
    MF(A1_, b0, 1, 0) MF(A1_, b1, 1, 1)                                       \
    MF(A2_, b0, 2, 0) MF(A2_, b1, 2, 1)                                       \
    MF(A3_, b0, 3, 0) MF(A3_, b1, 3, 1)                                       \
    if ((CG) < 6 || t < 8) {                                                  \
      const _Float16* wfp = wfrag + ((size_t)((p + 2) * 16 + wv * 4) * 64 + lane) * 8; \
      A0_ = *(const f16x8*)(wfp);                                             \
      A1_ = *(const f16x8*)(wfp + 512);                                       \
      A2_ = *(const f16x8*)(wfp + 1024);                                      \
      A3_ = *(const f16x8*)(wfp + 1536);                                      \
    }                                                                         \
  }

  for (int t = 0; t < 9; ++t) {
    SUB(0, q0, aA0, aA1, aA2, aA3)
    SUB(1, q1, aB0, aB1, aB2, aB3)
    SUB(2, q2, aA0, aA1, aA2, aA3)
    SUB(3, q3, aB0, aB1, aB2, aB3)
    SUB(4, q0, aA0, aA1, aA2, aA3)
    SUB(5, q1, aB0, aB1, aB2, aB3)
    SUB(6, q2, aA0, aA1, aA2, aA3)
    SUB(7, q3, aB0, aB1, aB2, aB3)
    Ocur = Onew;
    Wcmb = Wnew;
  }

  // --- epilogue: stores + GN partials ---
  const int colb = lane & 15, prow = (lane >> 4) * 4;
#pragma unroll
  for (int tt = 0; tt < 4; ++tt) {
    float s1 = 0.f, s2 = 0.f;
#pragma unroll
    for (int bt = 0; bt < 2; ++bt) {
      const int jj = bt * 16 + colb;
      const int row = ty * 4 + (jj >> 3), col = tx * 8 + (jj & 7);
      const f32x4 a = acc[tt][bt];
      if (col < WW) {
        float* op = out + ((size_t)(n * COUTC + wv * 64 + tt * 16 + prow)) * HW +
                    row * WW + col;
        op[0] = a[0];
        op[HW] = a[1];
        op[2 * HW] = a[2];
        op[3 * HW] = a[3];
      }
      s1 += a[0] + a[1] + a[2] + a[3];
      s2 += a[0] * a[0] + a[1] * a[1] + a[2] * a[2] + a[3] * a[3];
    }
    gr1[wv][tt][lane] = s1;
    gr2[wv][tt][lane] = s2;
  }
  __syncthreads();
  if (tid < 32) {
    const int wv2 = tid >> 3, tt2 = (tid >> 1) & 3, bit = tid & 1;
    float a1 = 0.f, a2 = 0.f;
#pragma unroll 8
    for (int l = 0; l < 32; ++l) {
      a1 += gr1[wv2][tt2][bit * 32 + l];
      a2 += gr2[wv2][tt2][bit * 32 + l];
    }
    float* pp = part + (((size_t)n * NT2 + rem) * GG + tid) * 2;
    pp[0] = a1;
    pp[1] = a2;
  }
}

// ---------------------------------------------------------------------------
// k3: reduce partials -> per (n,g) mean & rsigma
// ---------------------------------------------------------------------------
__global__ void __launch_bounds__(64) k3_stats(const float* __restrict__ part,
                                               float* __restrict__ stats) {
  const int b = blockIdx.x;                // 0..127
  const int n = b >> 5, g = b & 31;
  double s = 0.0, q = 0.0;
  for (int i = threadIdx.x; i < NT2; i += 64) {
    const float* pp = part + (((size_t)n * NT2 + i) * GG + g) * 2;
    s += pp[0];
    q += pp[1];
  }
#pragma unroll
  for (int off = 32; off > 0; off >>= 1) {
    s += __shfl_down(s, off);
    q += __shfl_down(q, off);
  }
  if (threadIdx.x == 0) {
    const double cnt = 8.0 * (double)HW;
    const double mean = s / cnt;
    const double var = q / cnt - mean * mean;
    stats[b * 2 + 0] = (float)mean;
    stats[b * 2 + 1] = (float)(1.0 / sqrt(var + (double)EPSF));
  }
}

// ---------------------------------------------------------------------------
// k4: in-place GroupNorm affine + ReLU on d_out
// ---------------------------------------------------------------------------
__global__ void __launch_bounds__(256) k4_norm(float* __restrict__ out,
                                               const float* __restrict__ stats,
                                               const float* __restrict__ gw,
                                               const float* __restrict__ gb) {
  const size_t i4 = (size_t)blockIdx.x * 256 + threadIdx.x;
  const size_t idx = i4 * 4;
  const int n = (int)(idx / ((size_t)COUTC * HW));
  const int r = (int)(idx % ((size_t)COUTC * HW));
  const int o = r / HW;
  const int g = o >> 3;
  const float mean = stats[(n * GG + g) * 2 + 0];
  const float rs = stats[(n * GG + g) * 2 + 1];
  const float sc = rs * gw[o];
  const float sh = gb[o] - mean * sc;
  float4 v = *(float4*)(out + idx);
  v.x = fmaxf(fmaf(v.x, sc, sh), 0.f);
  v.y = fmaxf(fmaf(v.y, sc, sh), 0.f);
  v.z = fmaxf(fmaf(v.z, sc, sh), 0.f);
  v.w = fmaxf(fmaf(v.w, sc, sh), 0.f);
  *(float4*)(out + idx) = v;
}

// ---------------------------------------------------------------------------
extern "C" void kernel_launch(void* const* d_in, const int* in_sizes, int n_in,
                              void* d_out, int out_size, void* d_ws, size_t ws_size,
                              hipStream_t stream) {
  const float* x    = (const float*)d_in[0];
  const float* w_tm = (const float*)d_in[1];
  const float* b_tm = (const float*)d_in[2];
  const float* w_tr = (const float*)d_in[3];
  const float* b_tr = (const float*)d_in[4];
  const float* w_def = (const float*)d_in[5];
  const float* gn_w = (const float*)d_in[6];
  const float* gn_b = (const float*)d_in[7];
  float* out = (float*)d_out;
  float* ws = (float*)d_ws;

  float* posy  = ws;                                     // 360000 f32
  float* posx  = ws + 360000;                            // 360000 f32
  _Float16* wfrag = (_Float16*)(ws + 720000);            // 589824 fp16
  _Float16* wf6   = (_Float16*)(ws + 1014912);           // 36864 fp16
  _Float16* xh    = (_Float16*)(ws + 1033344);           // 10.24M fp16
  float* part  = ws + 6153344;                           // 4*325*32*2 = 83200 f32
  float* stats = ws + 6236544;                           // 256 f32

  hipLaunchKernelGGL(k0_wfrag, dim3(2304), dim3(256), 0, stream, w_def, wfrag);
  hipLaunchKernelGGL(k0b_wfrag6, dim3(144), dim3(256), 0, stream, w_tm, w_tr, wf6);
  hipLaunchKernelGGL(kt_nhwc, dim3(2512), dim3(256), 0, stream, x, xh);
  hipLaunchKernelGGL(k1_off, dim3(625), dim3(256), 0, stream,
                     xh, wf6, b_tm, b_tr, posy, posx);
  hipLaunchKernelGGL(k2_deform, dim3(NBAT * NT2), dim3(256), 0, stream,
                     xh, wfrag, posy, posx, out, part);
  hipLaunchKernelGGL(k3_stats, dim3(NBAT * GG), dim3(64), 0, stream, part, stats);
  hipLaunchKernelGGL(k4_norm, dim3(10000), dim3(256), 0, stream,
                     out, stats, gn_w, gn_b);
}